// Round 1
// baseline (513.410 us; speedup 1.0000x reference)
//
#include <hip/hip_runtime.h>
#include <math.h>

#define BB 4
#define CC 64
#define HH 128
#define WW 128
#define NPT 9
#define HP 130
#define WP 130
#define HW (HH*WW)
#define TPX 16   // pixels per block in fused kernel

// ---------------- kernel 0: transpose conv_w [co][k] -> Wt [k][co] ----------------
__global__ void k_transpose_w(const float* __restrict__ cw, float* __restrict__ wt) {
    int i = blockIdx.x * 256 + threadIdx.x;   // over 64*576
    if (i < 64 * 576) {
        int co = i / 576, k = i - co * 576;
        wt[k * 64 + co] = cw[i];
    }
}

// ---------------- kernel 1: offset (18ch) + sigmoid mask (9ch) 3x3 conv ----------------
__global__ __launch_bounds__(256) void k_offset_mask(
    const float* __restrict__ x,
    const float* __restrict__ pw, const float* __restrict__ pb,
    const float* __restrict__ mw, const float* __restrict__ mb,
    float* __restrict__ offs, float* __restrict__ mask)
{
    int boc = blockIdx.x;              // b*27 + oc
    int b = boc / 27, oc = boc - b * 27;
    int pix = blockIdx.y * 256 + threadIdx.x;   // 0..16383
    int h = pix >> 7, w = pix & 127;

    const float* wptr = (oc < 18) ? (pw + oc * CC * 9) : (mw + (oc - 18) * CC * 9);
    float acc = (oc < 18) ? pb[oc] : mb[oc - 18];

    const float* xb = x + (size_t)b * CC * HW;
    for (int ci = 0; ci < CC; ++ci) {
        const float* xc = xb + ci * HW;
        const float* wc = wptr + ci * 9;
        #pragma unroll
        for (int kh = 0; kh < 3; ++kh) {
            int xi = h + kh - 1;
            bool xok = (xi >= 0) && (xi < HH);
            #pragma unroll
            for (int kw = 0; kw < 3; ++kw) {
                int yi = w + kw - 1;
                float v = (xok && yi >= 0 && yi < WW) ? xc[xi * WW + yi] : 0.f;
                acc = fmaf(v, wc[kh * 3 + kw], acc);
            }
        }
    }
    if (oc < 18) {
        offs[((size_t)b * 18 + oc) * HW + pix] = acc;
    } else {
        mask[((size_t)b * 9 + (oc - 18)) * HW + pix] = 1.f / (1.f + expf(-acc));
    }
}

// ---------------- kernel 2: fused bilinear sampling + K=576 GEMM ----------------
__global__ __launch_bounds__(256) void k_deform_gemm(
    const float* __restrict__ x, const float* __restrict__ offs,
    const float* __restrict__ mask, const float* __restrict__ wt,
    float* __restrict__ out)
{
    __shared__ float s_xoff[576 * TPX];                 // [k][px]
    __shared__ int   s_qxlt[NPT * TPX], s_qylt[NPT * TPX];
    __shared__ int   s_qxrb[NPT * TPX], s_qyrb[NPT * TPX];
    __shared__ float s_glt[NPT * TPX], s_grb[NPT * TPX];
    __shared__ float s_glb[NPT * TPX], s_grt[NPT * TPX];
    __shared__ float s_mk[NPT * TPX];

    int blk = blockIdx.x;            // b*1024 + h*8 + wblk
    int wblk = blk & 7;
    int h = (blk >> 3) & 127;
    int b = blk >> 10;
    int w0 = wblk * TPX;
    int t = threadIdx.x;

    // ---- phase 0: geometry for 9 kernel points x 16 pixels ----
    if (t < NPT * TPX) {
        int n = t >> 4, px = t & 15;
        int w = w0 + px;
        float ox = offs[((size_t)b * 18 + n) * HW + h * WW + w];
        float oy = offs[((size_t)b * 18 + 9 + n) * HW + h * WW + w];
        float mk = mask[((size_t)b * 9 + n) * HW + h * WW + w];
        float pxf = ox + (float)(n / 3 - 1) + (float)(h + 1);
        float pyf = oy + (float)(n % 3 - 1) + (float)(w + 1);
        float fx = floorf(pxf), fy = floorf(pyf);
        float qxlt_f = fminf(fmaxf(fx, 0.f), (float)(HP - 1));
        float qylt_f = fminf(fmaxf(fy, 0.f), (float)(WP - 1));
        float qxrb_f = fminf(fmaxf(fx + 1.f, 0.f), (float)(HP - 1));
        float qyrb_f = fminf(fmaxf(fy + 1.f, 0.f), (float)(WP - 1));
        int qxlt = (int)qxlt_f, qylt = (int)qylt_f;
        int qxrb = (int)qxrb_f, qyrb = (int)qyrb_f;
        float pxc = fminf(fmaxf(pxf, 0.f), (float)(HP - 1));
        float pyc = fminf(fmaxf(pyf, 0.f), (float)(WP - 1));
        float ax = 1.f + (float)qxlt - pxc;     // (1 + (qx_lt - pxc))
        float bx = 1.f - ((float)qxrb - pxc);   // (1 - (qx_rb - pxc))
        float ay = 1.f + (float)qylt - pyc;
        float by = 1.f - ((float)qyrb - pyc);
        s_qxlt[t] = qxlt; s_qylt[t] = qylt;
        s_qxrb[t] = qxrb; s_qyrb[t] = qyrb;
        s_glt[t] = ax * ay;
        s_grb[t] = bx * by;
        s_glb[t] = ax * by;
        s_grt[t] = bx * ay;
        s_mk[t] = mk;
    }
    __syncthreads();

    // ---- phase 1: sample 576 x 16 values into LDS ----
    {
        int px = t & 15;
        int base_s = t >> 4;       // 0..15
        const float* xb = x + (size_t)b * CC * HW;
        #pragma unroll 4
        for (int j = 0; j < 36; ++j) {
            int s = base_s + j * 16;       // k index = ci*9 + n
            int ci = s / 9;
            int n = s - ci * 9;
            int g = n * 16 + px;
            int qxlt = s_qxlt[g], qylt = s_qylt[g];
            int qxrb = s_qxrb[g], qyrb = s_qyrb[g];
            const float* xc = xb + ci * HW;
            // padded-gather: xp[qx][qy] = x[qx-1][qy-1] if 1<=qx<=128 && 1<=qy<=128 else 0
            float vlt = (qxlt >= 1 && qxlt <= HH && qylt >= 1 && qylt <= WW) ? xc[(qxlt - 1) * WW + (qylt - 1)] : 0.f;
            float vrb = (qxrb >= 1 && qxrb <= HH && qyrb >= 1 && qyrb <= WW) ? xc[(qxrb - 1) * WW + (qyrb - 1)] : 0.f;
            float vlb = (qxlt >= 1 && qxlt <= HH && qyrb >= 1 && qyrb <= WW) ? xc[(qxlt - 1) * WW + (qyrb - 1)] : 0.f;
            float vrt = (qxrb >= 1 && qxrb <= HH && qylt >= 1 && qylt <= WW) ? xc[(qxrb - 1) * WW + (qylt - 1)] : 0.f;
            float val = s_glt[g] * vlt + s_grb[g] * vrb + s_glb[g] * vlb + s_grt[g] * vrt;
            s_xoff[s * TPX + px] = val * s_mk[g];
        }
    }
    __syncthreads();

    // ---- phase 2: GEMM  out[16px][64co], K = 576 ----
    {
        int px = t & 15;
        int co4 = t >> 4;                 // 0..15 -> covers co = co4*4 .. co4*4+3
        float4 acc = make_float4(0.f, 0.f, 0.f, 0.f);
        for (int k = 0; k < 576; ++k) {
            float xv = s_xoff[k * TPX + px];
            float4 wv = reinterpret_cast<const float4*>(wt + k * 64)[co4];
            acc.x = fmaf(xv, wv.x, acc.x);
            acc.y = fmaf(xv, wv.y, acc.y);
            acc.z = fmaf(xv, wv.z, acc.z);
            acc.w = fmaf(xv, wv.w, acc.w);
        }
        int w = w0 + px;
        size_t base = ((size_t)b * CC + co4 * 4) * HW + h * WW + w;
        out[base]          = acc.x;
        out[base + HW]     = acc.y;
        out[base + 2 * HW] = acc.z;
        out[base + 3 * HW] = acc.w;
    }
}

extern "C" void kernel_launch(void* const* d_in, const int* in_sizes, int n_in,
                              void* d_out, int out_size, void* d_ws, size_t ws_size,
                              hipStream_t stream) {
    const float* x  = (const float*)d_in[0];
    const float* pw = (const float*)d_in[1];
    const float* pb = (const float*)d_in[2];
    const float* mw = (const float*)d_in[3];
    const float* mb = (const float*)d_in[4];
    const float* cw = (const float*)d_in[5];
    float* out = (float*)d_out;

    float* offs  = (float*)d_ws;                       // 4*18*16384 floats
    float* maskp = offs + (size_t)BB * 18 * HW;        // 4*9*16384 floats
    float* wt    = maskp + (size_t)BB * 9 * HW;        // 576*64 floats

    hipLaunchKernelGGL(k_transpose_w, dim3((64 * 576 + 255) / 256), dim3(256), 0, stream, cw, wt);
    hipLaunchKernelGGL(k_offset_mask, dim3(BB * 27, HW / 256), dim3(256), 0, stream,
                       x, pw, pb, mw, mb, offs, maskp);
    hipLaunchKernelGGL(k_deform_gemm, dim3(BB * HH * (WW / TPX)), dim3(256), 0, stream,
                       x, offs, maskp, wt, out);
}

// Round 3
// 190.625 us; speedup vs baseline: 2.6933x; 2.6933x over previous
//
#include <hip/hip_runtime.h>
#include <hip/hip_bf16.h>
#include <math.h>

#define BB 4
#define CC 64
#define HH 128
#define WW 128
#define NPT 9
#define HW (HH*WW)

typedef __attribute__((ext_vector_type(8))) short bf16x8;
typedef __attribute__((ext_vector_type(4))) float f32x4;

static __device__ __forceinline__ unsigned short f2bf(float f) {
    __hip_bfloat16 h = __float2bfloat16(f);
    return *reinterpret_cast<unsigned short*>(&h);
}

// ---------------- kernel 0: conv_w [co][ci*9+n] -> wtt bf16 [co][n*64+ci] ----------------
__global__ void k_prep_w(const float* __restrict__ cw, unsigned short* __restrict__ wtt) {
    int i = blockIdx.x * 256 + threadIdx.x;   // over 64*576
    if (i < 64 * 576) {
        int co = i / 576, k = i - co * 576;
        int ci = k / 9, n = k - ci * 9;
        wtt[co * 576 + n * 64 + ci] = f2bf(cw[i]);
    }
}

// ---------------- kernel 1: offset(18ch)+mask(9ch) conv, 9 oc per block ----------------
__global__ __launch_bounds__(256) void k_offset_mask(
    const float* __restrict__ x,
    const float* __restrict__ pw, const float* __restrict__ pb,
    const float* __restrict__ mw, const float* __restrict__ mb,
    float* __restrict__ offs, float* __restrict__ mask)
{
    int bog = blockIdx.x;              // b*3 + ocg
    int b = bog / 3, ocg = bog - b * 3;
    int pix = blockIdx.y * 256 + threadIdx.x;   // 0..16383
    int h = pix >> 7, w = pix & 127;

    const float* wbase = (ocg < 2) ? (pw + ocg * 9 * 576) : mw;
    const float* bbase = (ocg < 2) ? (pb + ocg * 9) : mb;

    float acc[9];
    #pragma unroll
    for (int oc = 0; oc < 9; ++oc) acc[oc] = bbase[oc];

    bool hu = h > 0, hd = h < HH - 1, wl = w > 0, wr = w < WW - 1;
    const float* xb = x + (size_t)b * CC * HW + pix;

    for (int ci = 0; ci < CC; ++ci) {
        const float* xc = xb + ci * HW;
        float v[9];
        v[0] = (hu && wl) ? xc[-WW - 1] : 0.f;
        v[1] = hu ? xc[-WW] : 0.f;
        v[2] = (hu && wr) ? xc[-WW + 1] : 0.f;
        v[3] = wl ? xc[-1] : 0.f;
        v[4] = xc[0];
        v[5] = wr ? xc[1] : 0.f;
        v[6] = (hd && wl) ? xc[WW - 1] : 0.f;
        v[7] = hd ? xc[WW] : 0.f;
        v[8] = (hd && wr) ? xc[WW + 1] : 0.f;
        const float* wc = wbase + ci * 9;
        #pragma unroll
        for (int oc = 0; oc < 9; ++oc) {
            #pragma unroll
            for (int tp = 0; tp < 9; ++tp) {
                acc[oc] = fmaf(v[tp], wc[oc * 576 + tp], acc[oc]);
            }
        }
    }
    if (ocg < 2) {
        #pragma unroll
        for (int oc = 0; oc < 9; ++oc)
            offs[((size_t)b * 18 + ocg * 9 + oc) * HW + pix] = acc[oc];
    } else {
        #pragma unroll
        for (int oc = 0; oc < 9; ++oc)
            mask[((size_t)b * 9 + oc) * HW + pix] = 1.f / (1.f + expf(-acc[oc]));
    }
}

// ---------------- kernel 2: fused bilinear sampling + MFMA GEMM ----------------
// block: 64 px (one h-row chunk) x 64 co, K=576 as 9 n-groups of 64 ci.
__global__ __launch_bounds__(256) void k_deform_mfma(
    const float* __restrict__ x, const float* __restrict__ offs,
    const float* __restrict__ mask, const unsigned short* __restrict__ wtt,
    float* __restrict__ out)
{
    __shared__ int s_geo[576 * 8];          // [n*64+px][a0 a1 a2 a3 w0 w1 w2 w3] 18432 B
    __shared__ unsigned int s_xoff[2048];   // [64 px][64 ci] bf16, XOR-swizzled, 8192 B

    int blk = blockIdx.x;            // b*256 + h*2 + wblk
    int wblk = blk & 1;
    int h = (blk >> 1) & 127;
    int b = blk >> 8;                // 4 batches: bits 8..9
    int w0 = wblk * 64;
    int t = threadIdx.x;
    int ln = t & 63, wid = t >> 6;
    int ln15 = ln & 15, lhi = ln >> 4;

    // ---- phase G: geometry for 9 n x 64 px ----
    for (int idx = t; idx < NPT * 64; idx += 256) {
        int n = idx >> 6, px = idx & 63;
        int w = w0 + px;
        float ox = offs[((size_t)b * 18 + n) * HW + h * WW + w];
        float oy = offs[((size_t)b * 18 + 9 + n) * HW + h * WW + w];
        float mk = mask[((size_t)b * 9 + n) * HW + h * WW + w];
        float pxf = ox + (float)(n / 3 - 1) + (float)(h + 1);
        float pyf = oy + (float)(n % 3 - 1) + (float)(w + 1);
        float fx = floorf(pxf), fy = floorf(pyf);
        int qxlt = (int)fminf(fmaxf(fx, 0.f), 129.f);
        int qylt = (int)fminf(fmaxf(fy, 0.f), 129.f);
        int qxrb = (int)fminf(fmaxf(fx + 1.f, 0.f), 129.f);
        int qyrb = (int)fminf(fmaxf(fy + 1.f, 0.f), 129.f);
        float pxc = fminf(fmaxf(pxf, 0.f), 129.f);
        float pyc = fminf(fmaxf(pyf, 0.f), 129.f);
        float ax = 1.f + (float)qxlt - pxc;
        float bx = 1.f - ((float)qxrb - pxc);
        float ay = 1.f + (float)qylt - pyc;
        float by = 1.f - ((float)qyrb - pyc);
        float glt = ax * ay * mk, grb = bx * by * mk;
        float glb = ax * by * mk, grt = bx * ay * mk;
        int a0, a1, a2, a3;
        // corner valid iff inside unpadded image: 1<=q<=128; else weight->0, addr->0 (safe)
        {
            bool v0 = qxlt >= 1 && qxlt <= HH && qylt >= 1 && qylt <= WW;
            bool v1 = qxrb >= 1 && qxrb <= HH && qyrb >= 1 && qyrb <= WW;
            bool v2 = qxlt >= 1 && qxlt <= HH && qyrb >= 1 && qyrb <= WW;
            bool v3 = qxrb >= 1 && qxrb <= HH && qylt >= 1 && qylt <= WW;
            a0 = v0 ? ((qxlt - 1) * WW + (qylt - 1)) : 0; if (!v0) glt = 0.f;
            a1 = v1 ? ((qxrb - 1) * WW + (qyrb - 1)) : 0; if (!v1) grb = 0.f;
            a2 = v2 ? ((qxlt - 1) * WW + (qyrb - 1)) : 0; if (!v2) glb = 0.f;
            a3 = v3 ? ((qxrb - 1) * WW + (qylt - 1)) : 0; if (!v3) grt = 0.f;
        }
        int* g = &s_geo[idx * 8];
        g[0] = a0; g[1] = a1; g[2] = a2; g[3] = a3;
        reinterpret_cast<float*>(g)[4] = glt;
        reinterpret_cast<float*>(g)[5] = grb;
        reinterpret_cast<float*>(g)[6] = glb;
        reinterpret_cast<float*>(g)[7] = grt;
    }
    __syncthreads();

    f32x4 acc[4];
    #pragma unroll
    for (int g = 0; g < 4; ++g) {
        acc[g][0] = 0.f; acc[g][1] = 0.f; acc[g][2] = 0.f; acc[g][3] = 0.f;
    }

    const unsigned short* wrow = wtt + (size_t)(wid * 16 + ln15) * 576;
    const float* xb = x + (size_t)b * CC * HW;
    int px = t & 63;            // sampling role: lane = px
    int cig = t >> 6;           // 16-ci group
    char* xoff_base = reinterpret_cast<char*>(s_xoff);

    for (int n = 0; n < NPT; ++n) {
        // B fragments for this n (global, L2-hot; consumed after the barrier)
        bf16x8 bf0 = *reinterpret_cast<const bf16x8*>(wrow + n * 64 + lhi * 8);
        bf16x8 bf1 = *reinterpret_cast<const bf16x8*>(wrow + n * 64 + 32 + lhi * 8);

        // ---- sampling: 16 ci per thread for its px ----
        const int* gp = &s_geo[(n * 64 + px) * 8];
        int a0 = gp[0], a1 = gp[1], a2 = gp[2], a3 = gp[3];
        float glt = reinterpret_cast<const float*>(gp)[4];
        float grb = reinterpret_cast<const float*>(gp)[5];
        float glb = reinterpret_cast<const float*>(gp)[6];
        float grt = reinterpret_cast<const float*>(gp)[7];

        unsigned int pk[8];
        #pragma unroll
        for (int i = 0; i < 16; i += 2) {
            const float* xc0 = xb + (size_t)(cig * 16 + i) * HW;
            const float* xc1 = xc0 + HW;
            float va = glt * xc0[a0] + grb * xc0[a1] + glb * xc0[a2] + grt * xc0[a3];
            float vb = glt * xc1[a0] + grb * xc1[a1] + glb * xc1[a2] + grt * xc1[a3];
            pk[i >> 1] = (unsigned int)f2bf(va) | ((unsigned int)f2bf(vb) << 16);
        }
        {
            char* base = xoff_base + px * 128;
            int sw = (px & 7) << 4;
            *reinterpret_cast<int4*>(base + ((cig * 32) ^ sw)) = *reinterpret_cast<int4*>(&pk[0]);
            *reinterpret_cast<int4*>(base + ((cig * 32 + 16) ^ sw)) = *reinterpret_cast<int4*>(&pk[4]);
        }
        __syncthreads();

        // ---- MFMA: 2 k-steps x 4 px-groups ----
        #pragma unroll
        for (int s2 = 0; s2 < 2; ++s2) {
            bf16x8 bfr = s2 ? bf1 : bf0;
            #pragma unroll
            for (int g = 0; g < 4; ++g) {
                int row = g * 16 + ln15;
                int cb2 = (s2 * 32 + lhi * 8) * 2;
                bf16x8 af = *reinterpret_cast<const bf16x8*>(
                    xoff_base + row * 128 + (cb2 ^ ((row & 7) << 4)));
                acc[g] = __builtin_amdgcn_mfma_f32_16x16x32_bf16(af, bfr, acc[g], 0, 0, 0);
            }
        }
        __syncthreads();
    }

    // ---- epilogue: lane holds co = wid*16 + ln15, px = g*16 + lhi*4 + r ----
    int co = wid * 16 + ln15;
    float* orow = out + ((size_t)b * CC + co) * HW + h * WW + w0;
    #pragma unroll
    for (int g = 0; g < 4; ++g) {
        *reinterpret_cast<float4*>(orow + g * 16 + lhi * 4) =
            *reinterpret_cast<float4*>(&acc[g]);
    }
}

extern "C" void kernel_launch(void* const* d_in, const int* in_sizes, int n_in,
                              void* d_out, int out_size, void* d_ws, size_t ws_size,
                              hipStream_t stream) {
    const float* x  = (const float*)d_in[0];
    const float* pw = (const float*)d_in[1];
    const float* pb = (const float*)d_in[2];
    const float* mw = (const float*)d_in[3];
    const float* mb = (const float*)d_in[4];
    const float* cw = (const float*)d_in[5];
    float* out = (float*)d_out;

    float* offs  = (float*)d_ws;                              // 4*18*16384 f32
    float* maskp = offs + (size_t)BB * 18 * HW;               // 4*9*16384 f32
    unsigned short* wtt = (unsigned short*)(maskp + (size_t)BB * 9 * HW);  // 64*576 bf16

    hipLaunchKernelGGL(k_prep_w, dim3((64 * 576 + 255) / 256), dim3(256), 0, stream, cw, wtt);
    hipLaunchKernelGGL(k_offset_mask, dim3(BB * 3, HW / 256), dim3(256), 0, stream,
                       x, pw, pb, mw, mb, offs, maskp);
    hipLaunchKernelGGL(k_deform_mfma, dim3(BB * HH * 2), dim3(256), 0, stream,
                       x, offs, maskp, wtt, out);
}

// Round 4
// 189.038 us; speedup vs baseline: 2.7159x; 1.0084x over previous
//
#include <hip/hip_runtime.h>
#include <hip/hip_bf16.h>
#include <math.h>

#define BB 4
#define CC 64
#define HH 128
#define WW 128
#define NPT 9
#define HW (HH*WW)

typedef __attribute__((ext_vector_type(8))) short bf16x8;
typedef __attribute__((ext_vector_type(4))) float f32x4;

static __device__ __forceinline__ unsigned short f2bf(float f) {
    __hip_bfloat16 h = __float2bfloat16(f);
    return *reinterpret_cast<unsigned short*>(&h);
}

// ---------------- kernel 0: conv_w [co][ci*9+n] -> wtt bf16 [co][n*64+ci] ----------------
__global__ void k_prep_w(const float* __restrict__ cw, unsigned short* __restrict__ wtt) {
    int i = blockIdx.x * 256 + threadIdx.x;   // over 64*576
    if (i < 64 * 576) {
        int co = i / 576, k = i - co * 576;
        int ci = k / 9, n = k - ci * 9;
        wtt[co * 576 + n * 64 + ci] = f2bf(cw[i]);
    }
}

// ---------------- kernel 1: offset(18ch)+mask(9ch) conv, 9 oc per block ----------------
__global__ __launch_bounds__(256) void k_offset_mask(
    const float* __restrict__ x,
    const float* __restrict__ pw, const float* __restrict__ pb,
    const float* __restrict__ mw, const float* __restrict__ mb,
    float* __restrict__ offs, float* __restrict__ mask)
{
    int bog = blockIdx.x;              // b*3 + ocg
    int b = bog / 3, ocg = bog - b * 3;
    int pix = blockIdx.y * 256 + threadIdx.x;   // 0..16383
    int h = pix >> 7, w = pix & 127;

    const float* wbase = (ocg < 2) ? (pw + ocg * 9 * 576) : mw;
    const float* bbase = (ocg < 2) ? (pb + ocg * 9) : mb;

    float acc[9];
    #pragma unroll
    for (int oc = 0; oc < 9; ++oc) acc[oc] = bbase[oc];

    bool hu = h > 0, hd = h < HH - 1, wl = w > 0, wr = w < WW - 1;
    const float* xb = x + (size_t)b * CC * HW + pix;

    for (int ci = 0; ci < CC; ++ci) {
        const float* xc = xb + ci * HW;
        float v[9];
        v[0] = (hu && wl) ? xc[-WW - 1] : 0.f;
        v[1] = hu ? xc[-WW] : 0.f;
        v[2] = (hu && wr) ? xc[-WW + 1] : 0.f;
        v[3] = wl ? xc[-1] : 0.f;
        v[4] = xc[0];
        v[5] = wr ? xc[1] : 0.f;
        v[6] = (hd && wl) ? xc[WW - 1] : 0.f;
        v[7] = hd ? xc[WW] : 0.f;
        v[8] = (hd && wr) ? xc[WW + 1] : 0.f;
        const float* wc = wbase + ci * 9;
        #pragma unroll
        for (int oc = 0; oc < 9; ++oc) {
            #pragma unroll
            for (int tp = 0; tp < 9; ++tp) {
                acc[oc] = fmaf(v[tp], wc[oc * 576 + tp], acc[oc]);
            }
        }
    }
    if (ocg < 2) {
        #pragma unroll
        for (int oc = 0; oc < 9; ++oc)
            offs[((size_t)b * 18 + ocg * 9 + oc) * HW + pix] = acc[oc];
    } else {
        #pragma unroll
        for (int oc = 0; oc < 9; ++oc)
            mask[((size_t)b * 9 + oc) * HW + pix] = 1.f / (1.f + expf(-acc[oc]));
    }
}

// ---------------- kernel 2: fused bilinear sampling + MFMA GEMM, 512 threads ----------------
// block: 64 px (one h-row chunk) x 64 co, K=576 as 9 n-groups of 64 ci.
// 8 waves: sampling = 8 ci/thread; MFMA = wave (wid&3)->co16, (wid>>2)->px-half.
__global__ __launch_bounds__(512, 6) void k_deform_mfma(
    const float* __restrict__ x, const float* __restrict__ offs,
    const float* __restrict__ mask, const unsigned short* __restrict__ wtt,
    float* __restrict__ out)
{
    __shared__ int s_geo[576 * 8];          // [n*64+px][a0 a1 a2 a3 w0 w1 w2 w3] 18432 B
    __shared__ unsigned int s_xoff[2048];   // [64 px][64 ci] bf16, XOR-swizzled, 8192 B

    int blk = blockIdx.x;            // b*256 + h*2 + wblk
    int wblk = blk & 1;
    int h = (blk >> 1) & 127;
    int b = blk >> 8;
    int w0 = wblk * 64;
    int t = threadIdx.x;
    int ln = t & 63, wid = t >> 6;          // 8 waves
    int ln15 = ln & 15, lhi = ln >> 4;

    // ---- phase G: geometry for 9 n x 64 px ----
    for (int idx = t; idx < NPT * 64; idx += 512) {
        int n = idx >> 6, px = idx & 63;
        int w = w0 + px;
        float ox = offs[((size_t)b * 18 + n) * HW + h * WW + w];
        float oy = offs[((size_t)b * 18 + 9 + n) * HW + h * WW + w];
        float mk = mask[((size_t)b * 9 + n) * HW + h * WW + w];
        float pxf = ox + (float)(n / 3 - 1) + (float)(h + 1);
        float pyf = oy + (float)(n % 3 - 1) + (float)(w + 1);
        float fx = floorf(pxf), fy = floorf(pyf);
        int qxlt = (int)fminf(fmaxf(fx, 0.f), 129.f);
        int qylt = (int)fminf(fmaxf(fy, 0.f), 129.f);
        int qxrb = (int)fminf(fmaxf(fx + 1.f, 0.f), 129.f);
        int qyrb = (int)fminf(fmaxf(fy + 1.f, 0.f), 129.f);
        float pxc = fminf(fmaxf(pxf, 0.f), 129.f);
        float pyc = fminf(fmaxf(pyf, 0.f), 129.f);
        float ax = 1.f + (float)qxlt - pxc;
        float bx = 1.f - ((float)qxrb - pxc);
        float ay = 1.f + (float)qylt - pyc;
        float by = 1.f - ((float)qyrb - pyc);
        float glt = ax * ay * mk, grb = bx * by * mk;
        float glb = ax * by * mk, grt = bx * ay * mk;
        int a0, a1, a2, a3;
        // corner valid iff inside unpadded image: 1<=q<=128; else weight->0, addr->0 (safe)
        {
            bool v0 = qxlt >= 1 && qxlt <= HH && qylt >= 1 && qylt <= WW;
            bool v1 = qxrb >= 1 && qxrb <= HH && qyrb >= 1 && qyrb <= WW;
            bool v2 = qxlt >= 1 && qxlt <= HH && qyrb >= 1 && qyrb <= WW;
            bool v3 = qxrb >= 1 && qxrb <= HH && qylt >= 1 && qylt <= WW;
            a0 = v0 ? ((qxlt - 1) * WW + (qylt - 1)) : 0; if (!v0) glt = 0.f;
            a1 = v1 ? ((qxrb - 1) * WW + (qyrb - 1)) : 0; if (!v1) grb = 0.f;
            a2 = v2 ? ((qxlt - 1) * WW + (qyrb - 1)) : 0; if (!v2) glb = 0.f;
            a3 = v3 ? ((qxrb - 1) * WW + (qylt - 1)) : 0; if (!v3) grt = 0.f;
        }
        int* g = &s_geo[idx * 8];
        g[0] = a0; g[1] = a1; g[2] = a2; g[3] = a3;
        reinterpret_cast<float*>(g)[4] = glt;
        reinterpret_cast<float*>(g)[5] = grb;
        reinterpret_cast<float*>(g)[6] = glb;
        reinterpret_cast<float*>(g)[7] = grt;
    }
    __syncthreads();

    f32x4 acc[2];
    #pragma unroll
    for (int g = 0; g < 2; ++g) {
        acc[g][0] = 0.f; acc[g][1] = 0.f; acc[g][2] = 0.f; acc[g][3] = 0.f;
    }

    const unsigned short* wrow = wtt + (size_t)((wid & 3) * 16 + ln15) * 576;
    const float* xb = x + (size_t)b * CC * HW;
    int px = t & 63;            // sampling role: lane chunk = px
    int cig = t >> 6;           // 8-ci group (0..7)
    char* xoff_base = reinterpret_cast<char*>(s_xoff);
    int ghalf = wid >> 2;       // px-half for MFMA role

    for (int n = 0; n < NPT; ++n) {
        // B fragments for this n (global, L2-hot; consumed after the barrier)
        bf16x8 bf0 = *reinterpret_cast<const bf16x8*>(wrow + n * 64 + lhi * 8);
        bf16x8 bf1 = *reinterpret_cast<const bf16x8*>(wrow + n * 64 + 32 + lhi * 8);

        // ---- sampling: 8 ci per thread for its px ----
        const int* gp = &s_geo[(n * 64 + px) * 8];
        int a0 = gp[0], a1 = gp[1], a2 = gp[2], a3 = gp[3];
        float glt = reinterpret_cast<const float*>(gp)[4];
        float grb = reinterpret_cast<const float*>(gp)[5];
        float glb = reinterpret_cast<const float*>(gp)[6];
        float grt = reinterpret_cast<const float*>(gp)[7];

        // issue all 32 loads before packing (MLP)
        float v0[8], v1[8], v2[8], v3[8];
        #pragma unroll
        for (int i = 0; i < 8; ++i) {
            const float* xc = xb + (size_t)(cig * 8 + i) * HW;
            v0[i] = xc[a0]; v1[i] = xc[a1]; v2[i] = xc[a2]; v3[i] = xc[a3];
        }
        unsigned int pk[4];
        #pragma unroll
        for (int i = 0; i < 8; i += 2) {
            float va = glt * v0[i]   + grb * v1[i]   + glb * v2[i]   + grt * v3[i];
            float vb = glt * v0[i+1] + grb * v1[i+1] + glb * v2[i+1] + grt * v3[i+1];
            pk[i >> 1] = (unsigned int)f2bf(va) | ((unsigned int)f2bf(vb) << 16);
        }
        {
            char* base = xoff_base + px * 128;
            int sw = (px & 7) << 4;
            *reinterpret_cast<int4*>(base + ((cig * 16) ^ sw)) = *reinterpret_cast<int4*>(&pk[0]);
        }
        __syncthreads();

        // ---- MFMA: 2 k-steps x 2 px-groups per wave ----
        #pragma unroll
        for (int s2 = 0; s2 < 2; ++s2) {
            bf16x8 bfr = s2 ? bf1 : bf0;
            #pragma unroll
            for (int g = 0; g < 2; ++g) {
                int row = (ghalf * 2 + g) * 16 + ln15;
                int cb2 = (s2 * 32 + lhi * 8) * 2;
                bf16x8 af = *reinterpret_cast<const bf16x8*>(
                    xoff_base + row * 128 + (cb2 ^ ((row & 7) << 4)));
                acc[g] = __builtin_amdgcn_mfma_f32_16x16x32_bf16(af, bfr, acc[g], 0, 0, 0);
            }
        }
        __syncthreads();
    }

    // ---- epilogue: lane holds co = (wid&3)*16 + ln15, px = (ghalf*2+g)*16 + lhi*4 + r ----
    int co = (wid & 3) * 16 + ln15;
    float* orow = out + ((size_t)b * CC + co) * HW + h * WW + w0;
    #pragma unroll
    for (int g = 0; g < 2; ++g) {
        *reinterpret_cast<float4*>(orow + (ghalf * 2 + g) * 16 + lhi * 4) =
            *reinterpret_cast<float4*>(&acc[g]);
    }
}

extern "C" void kernel_launch(void* const* d_in, const int* in_sizes, int n_in,
                              void* d_out, int out_size, void* d_ws, size_t ws_size,
                              hipStream_t stream) {
    const float* x  = (const float*)d_in[0];
    const float* pw = (const float*)d_in[1];
    const float* pb = (const float*)d_in[2];
    const float* mw = (const float*)d_in[3];
    const float* mb = (const float*)d_in[4];
    const float* cw = (const float*)d_in[5];
    float* out = (float*)d_out;

    float* offs  = (float*)d_ws;                              // 4*18*16384 f32
    float* maskp = offs + (size_t)BB * 18 * HW;               // 4*9*16384 f32
    unsigned short* wtt = (unsigned short*)(maskp + (size_t)BB * 9 * HW);  // 64*576 bf16

    hipLaunchKernelGGL(k_prep_w, dim3((64 * 576 + 255) / 256), dim3(256), 0, stream, cw, wtt);
    hipLaunchKernelGGL(k_offset_mask, dim3(BB * 3, HW / 256), dim3(256), 0, stream,
                       x, pw, pb, mw, mb, offs, maskp);
    hipLaunchKernelGGL(k_deform_mfma, dim3(BB * HH * 2), dim3(512), 0, stream,
                       x, offs, maskp, wtt, out);
}

// Round 5
// 103.079 us; speedup vs baseline: 4.9807x; 1.8339x over previous
//
#include <hip/hip_runtime.h>
#include <hip/hip_bf16.h>
#include <math.h>

#define BB 4
#define CC 64
#define HH 128
#define WW 128
#define NPT 9
#define HW (HH*WW)
#define HP 130
#define WP 130

typedef __attribute__((ext_vector_type(8))) short bf16x8;
typedef __attribute__((ext_vector_type(4))) float f32x4;

static __device__ __forceinline__ unsigned short f2bf(float f) {
    __hip_bfloat16 h = __float2bfloat16(f);
    return *reinterpret_cast<unsigned short*>(&h);
}
static __device__ __forceinline__ float bf2f(unsigned short u) {
    return __uint_as_float(((unsigned int)u) << 16);
}

// ---------------- kernel 0: conv_w [co][ci*9+n] -> wtt bf16 [co][n*64+ci] ----------------
__global__ void k_prep_w(const float* __restrict__ cw, unsigned short* __restrict__ wtt) {
    int i = blockIdx.x * 256 + threadIdx.x;   // over 64*576
    if (i < 64 * 576) {
        int co = i / 576, k = i - co * 576;
        int ci = k / 9, n = k - ci * 9;
        wtt[co * 576 + n * 64 + ci] = f2bf(cw[i]);
    }
}

// ---------------- kernel 0b: x NCHW fp32 -> xt NHWC bf16 (zero-padded borders via memset) ----
__global__ __launch_bounds__(256) void k_nhwc(const float* __restrict__ x,
                                              unsigned short* __restrict__ xt) {
    __shared__ float tile[64][129];
    int blk = blockIdx.x;          // b*128 + h
    int b = blk >> 7, h = blk & 127;
    int t = threadIdx.x;
    const float* xb = x + ((size_t)b * CC) * HW + h * WW;
    #pragma unroll
    for (int i = 0; i < 32; ++i) {
        int idx = i * 256 + t;             // over 64ci*128w
        int ci = idx >> 7, w = idx & 127;
        tile[ci][w] = xb[(size_t)ci * HW + w];
    }
    __syncthreads();
    unsigned short* xtb = xt + (((size_t)b * HP + (h + 1)) * WP + 1) * 64;
    #pragma unroll
    for (int i = 0; i < 32; ++i) {
        int idx = i * 256 + t;
        int w = idx >> 6, ci = idx & 63;
        xtb[(size_t)w * 64 + ci] = f2bf(tile[ci][w]);
    }
}

// ---------------- kernel 1: offset(18ch)+mask(9ch) conv, 9 oc per block ----------------
__global__ __launch_bounds__(256) void k_offset_mask(
    const float* __restrict__ x,
    const float* __restrict__ pw, const float* __restrict__ pb,
    const float* __restrict__ mw, const float* __restrict__ mb,
    float* __restrict__ offs, float* __restrict__ mask)
{
    int bog = blockIdx.x;              // b*3 + ocg
    int b = bog / 3, ocg = bog - b * 3;
    int pix = blockIdx.y * 256 + threadIdx.x;   // 0..16383
    int h = pix >> 7, w = pix & 127;

    const float* wbase = (ocg < 2) ? (pw + ocg * 9 * 576) : mw;
    const float* bbase = (ocg < 2) ? (pb + ocg * 9) : mb;

    float acc[9];
    #pragma unroll
    for (int oc = 0; oc < 9; ++oc) acc[oc] = bbase[oc];

    bool hu = h > 0, hd = h < HH - 1, wl = w > 0, wr = w < WW - 1;
    const float* xb = x + (size_t)b * CC * HW + pix;

    for (int ci = 0; ci < CC; ++ci) {
        const float* xc = xb + ci * HW;
        float v[9];
        v[0] = (hu && wl) ? xc[-WW - 1] : 0.f;
        v[1] = hu ? xc[-WW] : 0.f;
        v[2] = (hu && wr) ? xc[-WW + 1] : 0.f;
        v[3] = wl ? xc[-1] : 0.f;
        v[4] = xc[0];
        v[5] = wr ? xc[1] : 0.f;
        v[6] = (hd && wl) ? xc[WW - 1] : 0.f;
        v[7] = hd ? xc[WW] : 0.f;
        v[8] = (hd && wr) ? xc[WW + 1] : 0.f;
        const float* wc = wbase + ci * 9;
        #pragma unroll
        for (int oc = 0; oc < 9; ++oc) {
            #pragma unroll
            for (int tp = 0; tp < 9; ++tp) {
                acc[oc] = fmaf(v[tp], wc[oc * 576 + tp], acc[oc]);
            }
        }
    }
    if (ocg < 2) {
        #pragma unroll
        for (int oc = 0; oc < 9; ++oc)
            offs[((size_t)b * 18 + ocg * 9 + oc) * HW + pix] = acc[oc];
    } else {
        #pragma unroll
        for (int oc = 0; oc < 9; ++oc)
            mask[((size_t)b * 9 + oc) * HW + pix] = 1.f / (1.f + expf(-acc[oc]));
    }
}

// ---------------- kernel 2: fused bilinear sampling (NHWC bf16) + MFMA GEMM ----------------
// block: 64 px (one h-row chunk) x 64 co, K=576 as 9 n-groups of 64 ci. 512 threads.
// sampling lanes: px = t>>3, cig = t&7 (8 ci-vec chunks) -> coalesced 128B xt vectors.
__global__ __launch_bounds__(512, 4) void k_deform_mfma(
    const unsigned short* __restrict__ xt, const float* __restrict__ offs,
    const float* __restrict__ mask, const unsigned short* __restrict__ wtt,
    float* __restrict__ out)
{
    __shared__ int s_geo[576 * 8];          // [n*64+px][a0 a1 a2 a3 w0 w1 w2 w3] 18432 B
    __shared__ unsigned int s_xoff[2048];   // [64 px][64 ci] bf16, XOR-swizzled, 8192 B

    // XCD-chunked swizzle: 1024 blocks, 8 XCDs -> each XCD gets contiguous 128
    int blk0 = blockIdx.x;
    int blk = (blk0 & 7) * 128 + (blk0 >> 3);
    int wblk = blk & 1;
    int h = (blk >> 1) & 127;
    int b = blk >> 8;
    int w0 = wblk * 64;
    int t = threadIdx.x;
    int ln = t & 63, wid = t >> 6;          // 8 waves
    int ln15 = ln & 15, lhi = ln >> 4;

    // ---- phase G: geometry for 9 n x 64 px ----
    for (int idx = t; idx < NPT * 64; idx += 512) {
        int n = idx >> 6, px = idx & 63;
        int w = w0 + px;
        float ox = offs[((size_t)b * 18 + n) * HW + h * WW + w];
        float oy = offs[((size_t)b * 18 + 9 + n) * HW + h * WW + w];
        float mk = mask[((size_t)b * 9 + n) * HW + h * WW + w];
        float pxf = ox + (float)(n / 3 - 1) + (float)(h + 1);
        float pyf = oy + (float)(n % 3 - 1) + (float)(w + 1);
        float fx = floorf(pxf), fy = floorf(pyf);
        int qxlt = (int)fminf(fmaxf(fx, 0.f), 129.f);
        int qylt = (int)fminf(fmaxf(fy, 0.f), 129.f);
        int qxrb = (int)fminf(fmaxf(fx + 1.f, 0.f), 129.f);
        int qyrb = (int)fminf(fmaxf(fy + 1.f, 0.f), 129.f);
        float pxc = fminf(fmaxf(pxf, 0.f), 129.f);
        float pyc = fminf(fmaxf(pyf, 0.f), 129.f);
        float ax = 1.f + (float)qxlt - pxc;
        float bx = 1.f - ((float)qxrb - pxc);
        float ay = 1.f + (float)qylt - pyc;
        float by = 1.f - ((float)qyrb - pyc);
        // pads in xt are real zeros -> no validity masking needed (matches reference xp)
        int* g = &s_geo[idx * 8];
        g[0] = (qxlt * WP + qylt) * 64;
        g[1] = (qxrb * WP + qyrb) * 64;
        g[2] = (qxlt * WP + qyrb) * 64;
        g[3] = (qxrb * WP + qylt) * 64;
        reinterpret_cast<float*>(g)[4] = ax * ay * mk;
        reinterpret_cast<float*>(g)[5] = bx * by * mk;
        reinterpret_cast<float*>(g)[6] = ax * by * mk;
        reinterpret_cast<float*>(g)[7] = bx * ay * mk;
    }
    __syncthreads();

    f32x4 acc[2];
    #pragma unroll
    for (int g = 0; g < 2; ++g) {
        acc[g][0] = 0.f; acc[g][1] = 0.f; acc[g][2] = 0.f; acc[g][3] = 0.f;
    }

    const unsigned short* wrow = wtt + (size_t)((wid & 3) * 16 + ln15) * 576;
    const unsigned short* xtb = xt + (size_t)b * HP * WP * 64;
    int px_s = t >> 3;          // sampling: 64 px
    int cig_s = t & 7;          // 8-ci-vec chunk (8 ci each)
    char* xoff_base = reinterpret_cast<char*>(s_xoff);
    int ghalf = wid >> 2;       // px-half for MFMA role

    for (int n = 0; n < NPT; ++n) {
        // B fragments for this n (global, L2-hot; consumed after the barrier)
        bf16x8 bf0 = *reinterpret_cast<const bf16x8*>(wrow + n * 64 + lhi * 8);
        bf16x8 bf1 = *reinterpret_cast<const bf16x8*>(wrow + n * 64 + 32 + lhi * 8);

        // ---- sampling: 8 ci (one bf16x8 per corner) for this thread's px ----
        const int* gp = &s_geo[(n * 64 + px_s) * 8];
        int a0 = gp[0], a1 = gp[1], a2 = gp[2], a3 = gp[3];
        float glt = reinterpret_cast<const float*>(gp)[4];
        float grb = reinterpret_cast<const float*>(gp)[5];
        float glb = reinterpret_cast<const float*>(gp)[6];
        float grt = reinterpret_cast<const float*>(gp)[7];

        int coff = cig_s * 8;
        bf16x8 c0 = *reinterpret_cast<const bf16x8*>(xtb + a0 + coff);
        bf16x8 c1 = *reinterpret_cast<const bf16x8*>(xtb + a1 + coff);
        bf16x8 c2 = *reinterpret_cast<const bf16x8*>(xtb + a2 + coff);
        bf16x8 c3 = *reinterpret_cast<const bf16x8*>(xtb + a3 + coff);

        unsigned int pk[4];
        #pragma unroll
        for (int i = 0; i < 4; ++i) {
            float va = glt * bf2f((unsigned short)c0[2*i])   + grb * bf2f((unsigned short)c1[2*i])
                     + glb * bf2f((unsigned short)c2[2*i])   + grt * bf2f((unsigned short)c3[2*i]);
            float vb = glt * bf2f((unsigned short)c0[2*i+1]) + grb * bf2f((unsigned short)c1[2*i+1])
                     + glb * bf2f((unsigned short)c2[2*i+1]) + grt * bf2f((unsigned short)c3[2*i+1]);
            pk[i] = (unsigned int)f2bf(va) | ((unsigned int)f2bf(vb) << 16);
        }
        {
            char* base = xoff_base + px_s * 128;
            int sw = (px_s & 7) << 4;
            *reinterpret_cast<int4*>(base + ((cig_s * 16) ^ sw)) = *reinterpret_cast<int4*>(&pk[0]);
        }
        __syncthreads();

        // ---- MFMA: 2 k-steps x 2 px-groups per wave ----
        #pragma unroll
        for (int s2 = 0; s2 < 2; ++s2) {
            bf16x8 bfr = s2 ? bf1 : bf0;
            #pragma unroll
            for (int g = 0; g < 2; ++g) {
                int row = (ghalf * 2 + g) * 16 + ln15;
                int cb2 = (s2 * 32 + lhi * 8) * 2;
                bf16x8 af = *reinterpret_cast<const bf16x8*>(
                    xoff_base + row * 128 + (cb2 ^ ((row & 7) << 4)));
                acc[g] = __builtin_amdgcn_mfma_f32_16x16x32_bf16(af, bfr, acc[g], 0, 0, 0);
            }
        }
        __syncthreads();
    }

    // ---- epilogue: lane holds co = (wid&3)*16 + ln15, px = (ghalf*2+g)*16 + lhi*4 + r ----
    int co = (wid & 3) * 16 + ln15;
    float* orow = out + ((size_t)b * CC + co) * HW + h * WW + w0;
    #pragma unroll
    for (int g = 0; g < 2; ++g) {
        *reinterpret_cast<float4*>(orow + (ghalf * 2 + g) * 16 + lhi * 4) =
            *reinterpret_cast<float4*>(&acc[g]);
    }
}

extern "C" void kernel_launch(void* const* d_in, const int* in_sizes, int n_in,
                              void* d_out, int out_size, void* d_ws, size_t ws_size,
                              hipStream_t stream) {
    const float* x  = (const float*)d_in[0];
    const float* pw = (const float*)d_in[1];
    const float* pb = (const float*)d_in[2];
    const float* mw = (const float*)d_in[3];
    const float* mb = (const float*)d_in[4];
    const float* cw = (const float*)d_in[5];
    float* out = (float*)d_out;

    // ws layout (bytes):
    char* wsc = (char*)d_ws;
    unsigned short* xt  = (unsigned short*)wsc;                         // 4*130*130*64 bf16 = 8,652,800 B
    size_t xt_bytes = (size_t)BB * HP * WP * 64 * sizeof(unsigned short);
    float* offs  = (float*)(wsc + ((xt_bytes + 255) & ~(size_t)255));   // 4*18*16384 f32
    float* maskp = offs + (size_t)BB * 18 * HW;                         // 4*9*16384 f32
    unsigned short* wtt = (unsigned short*)(maskp + (size_t)BB * 9 * HW);  // 64*576 bf16

    hipMemsetAsync(xt, 0, xt_bytes, stream);
    hipLaunchKernelGGL(k_prep_w, dim3((64 * 576 + 255) / 256), dim3(256), 0, stream, cw, wtt);
    hipLaunchKernelGGL(k_nhwc, dim3(BB * HH), dim3(256), 0, stream, x, xt);
    hipLaunchKernelGGL(k_offset_mask, dim3(BB * 3, HW / 256), dim3(256), 0, stream,
                       x, pw, pb, mw, mb, offs, maskp);
    hipLaunchKernelGGL(k_deform_mfma, dim3(BB * HH * 2), dim3(512), 0, stream,
                       xt, offs, maskp, wtt, out);
}

// Round 6
// 78.135 us; speedup vs baseline: 6.5708x; 1.3192x over previous
//
#include <hip/hip_runtime.h>
#include <hip/hip_bf16.h>
#include <math.h>

#define BB 4
#define CC 64
#define HH 128
#define WW 128
#define NPT 9
#define HW (HH*WW)
#define HP 130
#define WP 130

typedef __attribute__((ext_vector_type(8))) short bf16x8;
typedef __attribute__((ext_vector_type(4))) float f32x4;

static __device__ __forceinline__ unsigned short f2bf(float f) {
    __hip_bfloat16 h = __float2bfloat16(f);
    return *reinterpret_cast<unsigned short*>(&h);
}
static __device__ __forceinline__ float bf2f(unsigned short u) {
    return __uint_as_float(((unsigned int)u) << 16);
}

// ---------------- kernel 0: conv_w [co][ci*9+n] -> wtt bf16 [co][n*64+ci] ----------------
__global__ void k_prep_w(const float* __restrict__ cw, unsigned short* __restrict__ wtt) {
    int i = blockIdx.x * 256 + threadIdx.x;   // over 64*576
    if (i < 64 * 576) {
        int co = i / 576, k = i - co * 576;
        int ci = k / 9, n = k - ci * 9;
        wtt[co * 576 + n * 64 + ci] = f2bf(cw[i]);
    }
}

// ---------------- kernel 0a: offset/mask weights -> fragment-ordered wttB + biases ----------
// flat index = (((n*2+s2)*4+lhi)*32 + co)*8 + j ; ci = s2*32+lhi*8+j
__global__ void k_prep_w27(const float* __restrict__ pw, const float* __restrict__ pb,
                           const float* __restrict__ mw, const float* __restrict__ mb,
                           unsigned short* __restrict__ wttB, float* __restrict__ b27) {
    int i = blockIdx.x * 256 + threadIdx.x;   // over 18432 + 32
    if (i < 18432) {
        int j   = i & 7;
        int co  = (i >> 3) & 31;
        int lhi = (i >> 8) & 3;
        int s2  = (i >> 10) & 1;
        int n   = i >> 11;
        int ci  = s2 * 32 + lhi * 8 + j;
        float v = 0.f;
        if (co < 18) v = pw[(co * 64 + ci) * 9 + n];
        else if (co < 27) v = mw[((co - 18) * 64 + ci) * 9 + n];
        wttB[i] = f2bf(v);
    } else if (i < 18432 + 32) {
        int co = i - 18432;
        b27[co] = (co < 18) ? pb[co] : (co < 27 ? mb[co - 18] : 0.f);
    }
}

// ---------------- kernel 0b: x NCHW fp32 -> xt NHWC bf16 (zero-padded borders via memset) ----
__global__ __launch_bounds__(256) void k_nhwc(const float* __restrict__ x,
                                              unsigned short* __restrict__ xt) {
    __shared__ float tile[64][129];
    int blk = blockIdx.x;          // b*128 + h
    int b = blk >> 7, h = blk & 127;
    int t = threadIdx.x;
    const float* xb = x + ((size_t)b * CC) * HW + h * WW;
    #pragma unroll
    for (int i = 0; i < 32; ++i) {
        int idx = i * 256 + t;             // over 64ci*128w
        int ci = idx >> 7, w = idx & 127;
        tile[ci][w] = xb[(size_t)ci * HW + w];
    }
    __syncthreads();
    unsigned short* xtb = xt + (((size_t)b * HP + (h + 1)) * WP + 1) * 64;
    #pragma unroll
    for (int i = 0; i < 32; ++i) {
        int idx = i * 256 + t;
        int w = idx >> 6, ci = idx & 63;
        xtb[(size_t)w * 64 + ci] = f2bf(tile[ci][w]);
    }
}

// ---------------- kernel 1: offset(18)+mask(9) conv via MFMA on NHWC xt ----------------
// block: 64 px (half h-row) x 32 co; 8 waves, each a 16px x 16co quadrant; no LDS/barriers.
__global__ __launch_bounds__(512) void k_om_mfma(
    const unsigned short* __restrict__ xt, const unsigned short* __restrict__ wttB,
    const float* __restrict__ b27,
    float* __restrict__ offs, float* __restrict__ mask)
{
    int blk = blockIdx.x;            // b*256 + h*2 + wblk
    int wblk = blk & 1;
    int h = (blk >> 1) & 127;
    int b = blk >> 8;
    int w0 = wblk * 64;
    int t = threadIdx.x;
    int ln = t & 63, wid = t >> 6;
    int ln15 = ln & 15, lhi = ln >> 4;
    int pxg = wid >> 1, coh = wid & 1;

    const unsigned short* xtb = xt + (size_t)b * HP * WP * 64;
    int px = pxg * 16 + ln15;

    f32x4 acc;
    acc[0] = 0.f; acc[1] = 0.f; acc[2] = 0.f; acc[3] = 0.f;

    #pragma unroll
    for (int n = 0; n < NPT; ++n) {
        int kh = n / 3, kw = n - kh * 3;
        // A row for tap n: xt[h+kh][w0+px+kw][ci]
        const unsigned short* arow = xtb + ((size_t)(h + kh) * WP + (w0 + px + kw)) * 64;
        #pragma unroll
        for (int s2 = 0; s2 < 2; ++s2) {
            bf16x8 af = *reinterpret_cast<const bf16x8*>(arow + s2 * 32 + lhi * 8);
            bf16x8 bf = *reinterpret_cast<const bf16x8*>(
                wttB + ((((n * 2 + s2) * 4 + lhi) * 32) + coh * 16 + ln15) * 8);
            acc = __builtin_amdgcn_mfma_f32_16x16x32_bf16(af, bf, acc, 0, 0, 0);
        }
    }

    // epilogue: lane holds co = coh*16+ln15 (col), px rows = pxg*16 + lhi*4 + r
    int co = coh * 16 + ln15;
    float bias = b27[co];
    int prow = pxg * 16 + lhi * 4;
    if (co < 18) {
        float4 v;
        v.x = acc[0] + bias; v.y = acc[1] + bias;
        v.z = acc[2] + bias; v.w = acc[3] + bias;
        *reinterpret_cast<float4*>(&offs[((size_t)b * 18 + co) * HW + h * WW + w0 + prow]) = v;
    } else if (co < 27) {
        float4 v;
        v.x = 1.f / (1.f + expf(-(acc[0] + bias)));
        v.y = 1.f / (1.f + expf(-(acc[1] + bias)));
        v.z = 1.f / (1.f + expf(-(acc[2] + bias)));
        v.w = 1.f / (1.f + expf(-(acc[3] + bias)));
        *reinterpret_cast<float4*>(&mask[((size_t)b * 9 + (co - 18)) * HW + h * WW + w0 + prow]) = v;
    }
}

// ---------------- kernel 2: fused bilinear sampling (NHWC bf16) + MFMA GEMM ----------------
// block: 64 px (one h-row chunk) x 64 co, K=576 as 9 n-groups of 64 ci. 512 threads.
// sampling lanes: px = t>>3, cig = t&7 (8 ci-vec chunks) -> coalesced 128B xt vectors.
__global__ __launch_bounds__(512, 4) void k_deform_mfma(
    const unsigned short* __restrict__ xt, const float* __restrict__ offs,
    const float* __restrict__ mask, const unsigned short* __restrict__ wtt,
    float* __restrict__ out)
{
    __shared__ int s_geo[576 * 8];          // [n*64+px][a0 a1 a2 a3 w0 w1 w2 w3] 18432 B
    __shared__ unsigned int s_xoff[2048];   // [64 px][64 ci] bf16, XOR-swizzled, 8192 B

    // XCD-chunked swizzle: 1024 blocks, 8 XCDs -> each XCD gets contiguous 128
    int blk0 = blockIdx.x;
    int blk = (blk0 & 7) * 128 + (blk0 >> 3);
    int wblk = blk & 1;
    int h = (blk >> 1) & 127;
    int b = blk >> 8;
    int w0 = wblk * 64;
    int t = threadIdx.x;
    int ln = t & 63, wid = t >> 6;          // 8 waves
    int ln15 = ln & 15, lhi = ln >> 4;

    // ---- phase G: geometry for 9 n x 64 px ----
    for (int idx = t; idx < NPT * 64; idx += 512) {
        int n = idx >> 6, px = idx & 63;
        int w = w0 + px;
        float ox = offs[((size_t)b * 18 + n) * HW + h * WW + w];
        float oy = offs[((size_t)b * 18 + 9 + n) * HW + h * WW + w];
        float mk = mask[((size_t)b * 9 + n) * HW + h * WW + w];
        float pxf = ox + (float)(n / 3 - 1) + (float)(h + 1);
        float pyf = oy + (float)(n % 3 - 1) + (float)(w + 1);
        float fx = floorf(pxf), fy = floorf(pyf);
        int qxlt = (int)fminf(fmaxf(fx, 0.f), 129.f);
        int qylt = (int)fminf(fmaxf(fy, 0.f), 129.f);
        int qxrb = (int)fminf(fmaxf(fx + 1.f, 0.f), 129.f);
        int qyrb = (int)fminf(fmaxf(fy + 1.f, 0.f), 129.f);
        float pxc = fminf(fmaxf(pxf, 0.f), 129.f);
        float pyc = fminf(fmaxf(pyf, 0.f), 129.f);
        float ax = 1.f + (float)qxlt - pxc;
        float bx = 1.f - ((float)qxrb - pxc);
        float ay = 1.f + (float)qylt - pyc;
        float by = 1.f - ((float)qyrb - pyc);
        // pads in xt are real zeros -> no validity masking needed (matches reference xp)
        int* g = &s_geo[idx * 8];
        g[0] = (qxlt * WP + qylt) * 64;
        g[1] = (qxrb * WP + qyrb) * 64;
        g[2] = (qxlt * WP + qyrb) * 64;
        g[3] = (qxrb * WP + qylt) * 64;
        reinterpret_cast<float*>(g)[4] = ax * ay * mk;
        reinterpret_cast<float*>(g)[5] = bx * by * mk;
        reinterpret_cast<float*>(g)[6] = ax * by * mk;
        reinterpret_cast<float*>(g)[7] = bx * ay * mk;
    }
    __syncthreads();

    f32x4 acc[2];
    #pragma unroll
    for (int g = 0; g < 2; ++g) {
        acc[g][0] = 0.f; acc[g][1] = 0.f; acc[g][2] = 0.f; acc[g][3] = 0.f;
    }

    const unsigned short* wrow = wtt + (size_t)((wid & 3) * 16 + ln15) * 576;
    const unsigned short* xtb = xt + (size_t)b * HP * WP * 64;
    int px_s = t >> 3;          // sampling: 64 px
    int cig_s = t & 7;          // 8-ci-vec chunk (8 ci each)
    char* xoff_base = reinterpret_cast<char*>(s_xoff);
    int ghalf = wid >> 2;       // px-half for MFMA role

    for (int n = 0; n < NPT; ++n) {
        // B fragments for this n (global, L2-hot; consumed after the barrier)
        bf16x8 bf0 = *reinterpret_cast<const bf16x8*>(wrow + n * 64 + lhi * 8);
        bf16x8 bf1 = *reinterpret_cast<const bf16x8*>(wrow + n * 64 + 32 + lhi * 8);

        // ---- sampling: 8 ci (one bf16x8 per corner) for this thread's px ----
        const int* gp = &s_geo[(n * 64 + px_s) * 8];
        int a0 = gp[0], a1 = gp[1], a2 = gp[2], a3 = gp[3];
        float glt = reinterpret_cast<const float*>(gp)[4];
        float grb = reinterpret_cast<const float*>(gp)[5];
        float glb = reinterpret_cast<const float*>(gp)[6];
        float grt = reinterpret_cast<const float*>(gp)[7];

        int coff = cig_s * 8;
        bf16x8 c0 = *reinterpret_cast<const bf16x8*>(xtb + a0 + coff);
        bf16x8 c1 = *reinterpret_cast<const bf16x8*>(xtb + a1 + coff);
        bf16x8 c2 = *reinterpret_cast<const bf16x8*>(xtb + a2 + coff);
        bf16x8 c3 = *reinterpret_cast<const bf16x8*>(xtb + a3 + coff);

        unsigned int pk[4];
        #pragma unroll
        for (int i = 0; i < 4; ++i) {
            float va = glt * bf2f((unsigned short)c0[2*i])   + grb * bf2f((unsigned short)c1[2*i])
                     + glb * bf2f((unsigned short)c2[2*i])   + grt * bf2f((unsigned short)c3[2*i]);
            float vb = glt * bf2f((unsigned short)c0[2*i+1]) + grb * bf2f((unsigned short)c1[2*i+1])
                     + glb * bf2f((unsigned short)c2[2*i+1]) + grt * bf2f((unsigned short)c3[2*i+1]);
            pk[i] = (unsigned int)f2bf(va) | ((unsigned int)f2bf(vb) << 16);
        }
        {
            char* base = xoff_base + px_s * 128;
            int sw = (px_s & 7) << 4;
            *reinterpret_cast<int4*>(base + ((cig_s * 16) ^ sw)) = *reinterpret_cast<int4*>(&pk[0]);
        }
        __syncthreads();

        // ---- MFMA: 2 k-steps x 2 px-groups per wave ----
        #pragma unroll
        for (int s2 = 0; s2 < 2; ++s2) {
            bf16x8 bfr = s2 ? bf1 : bf0;
            #pragma unroll
            for (int g = 0; g < 2; ++g) {
                int row = (ghalf * 2 + g) * 16 + ln15;
                int cb2 = (s2 * 32 + lhi * 8) * 2;
                bf16x8 af = *reinterpret_cast<const bf16x8*>(
                    xoff_base + row * 128 + (cb2 ^ ((row & 7) << 4)));
                acc[g] = __builtin_amdgcn_mfma_f32_16x16x32_bf16(af, bfr, acc[g], 0, 0, 0);
            }
        }
        __syncthreads();
    }

    // ---- epilogue: lane holds co = (wid&3)*16 + ln15, px = (ghalf*2+g)*16 + lhi*4 + r ----
    int co = (wid & 3) * 16 + ln15;
    float* orow = out + ((size_t)b * CC + co) * HW + h * WW + w0;
    #pragma unroll
    for (int g = 0; g < 2; ++g) {
        *reinterpret_cast<float4*>(orow + (ghalf * 2 + g) * 16 + lhi * 4) =
            *reinterpret_cast<float4*>(&acc[g]);
    }
}

extern "C" void kernel_launch(void* const* d_in, const int* in_sizes, int n_in,
                              void* d_out, int out_size, void* d_ws, size_t ws_size,
                              hipStream_t stream) {
    const float* x  = (const float*)d_in[0];
    const float* pw = (const float*)d_in[1];
    const float* pb = (const float*)d_in[2];
    const float* mw = (const float*)d_in[3];
    const float* mb = (const float*)d_in[4];
    const float* cw = (const float*)d_in[5];
    float* out = (float*)d_out;

    // ws layout (bytes, 256-aligned sections):
    char* wsc = (char*)d_ws;
    unsigned short* xt  = (unsigned short*)wsc;                         // 4*130*130*64 bf16 = 8,652,800 B
    size_t off = ((size_t)BB * HP * WP * 64 * 2 + 255) & ~(size_t)255;
    float* offs  = (float*)(wsc + off);                                 // 4*18*16384 f32
    off += (size_t)BB * 18 * HW * 4;
    float* maskp = (float*)(wsc + off);                                 // 4*9*16384 f32
    off += (size_t)BB * 9 * HW * 4;
    unsigned short* wtt = (unsigned short*)(wsc + off);                 // 64*576 bf16
    off += (size_t)64 * 576 * 2;
    unsigned short* wttB = (unsigned short*)(wsc + off);                // 18432 bf16
    off += (size_t)18432 * 2 + 128;
    float* b27 = (float*)(wsc + ((off + 255) & ~(size_t)255));          // 32 f32

    hipMemsetAsync(xt, 0, (size_t)BB * HP * WP * 64 * 2, stream);
    hipLaunchKernelGGL(k_prep_w, dim3((64 * 576 + 255) / 256), dim3(256), 0, stream, cw, wtt);
    hipLaunchKernelGGL(k_prep_w27, dim3((18432 + 32 + 255) / 256), dim3(256), 0, stream,
                       pw, pb, mw, mb, wttB, b27);
    hipLaunchKernelGGL(k_nhwc, dim3(BB * HH), dim3(256), 0, stream, x, xt);
    hipLaunchKernelGGL(k_om_mfma, dim3(BB * HH * 2), dim3(512), 0, stream,
                       xt, wttB, b27, offs, maskp);
    hipLaunchKernelGGL(k_deform_mfma, dim3(BB * HH * 2), dim3(512), 0, stream,
                       xt, offs, maskp, wtt, out);
}

// Round 7
// 75.852 us; speedup vs baseline: 6.7685x; 1.0301x over previous
//
#include <hip/hip_runtime.h>
#include <hip/hip_bf16.h>
#include <math.h>

#define BB 4
#define CC 64
#define HH 128
#define WW 128
#define NPT 9
#define HW (HH*WW)
#define HP 130
#define WP 130

typedef __attribute__((ext_vector_type(8))) short bf16x8;
typedef __attribute__((ext_vector_type(4))) float f32x4;

static __device__ __forceinline__ unsigned short f2bf(float f) {
    __hip_bfloat16 h = __float2bfloat16(f);
    return *reinterpret_cast<unsigned short*>(&h);
}
static __device__ __forceinline__ float bf2f(unsigned short u) {
    return __uint_as_float(((unsigned int)u) << 16);
}

// ---------------- kernel 0: conv_w [co][ci*9+n] -> wtt bf16 [co][n*64+ci] ----------------
__global__ void k_prep_w(const float* __restrict__ cw, unsigned short* __restrict__ wtt) {
    int i = blockIdx.x * 256 + threadIdx.x;   // over 64*576
    if (i < 64 * 576) {
        int co = i / 576, k = i - co * 576;
        int ci = k / 9, n = k - ci * 9;
        wtt[co * 576 + n * 64 + ci] = f2bf(cw[i]);
    }
}

// ---------------- kernel 0a: offset/mask weights -> fragment-ordered wttB + biases ----------
// flat index = (((n*2+s2)*4+lhi)*32 + co)*8 + j ; ci = s2*32+lhi*8+j
__global__ void k_prep_w27(const float* __restrict__ pw, const float* __restrict__ pb,
                           const float* __restrict__ mw, const float* __restrict__ mb,
                           unsigned short* __restrict__ wttB, float* __restrict__ b27) {
    int i = blockIdx.x * 256 + threadIdx.x;   // over 18432 + 32
    if (i < 18432) {
        int j   = i & 7;
        int co  = (i >> 3) & 31;
        int lhi = (i >> 8) & 3;
        int s2  = (i >> 10) & 1;
        int n   = i >> 11;
        int ci  = s2 * 32 + lhi * 8 + j;
        float v = 0.f;
        if (co < 18) v = pw[(co * 64 + ci) * 9 + n];
        else if (co < 27) v = mw[((co - 18) * 64 + ci) * 9 + n];
        wttB[i] = f2bf(v);
    } else if (i < 18432 + 32) {
        int co = i - 18432;
        b27[co] = (co < 18) ? pb[co] : (co < 27 ? mb[co - 18] : 0.f);
    }
}

// ---------------- kernel 0c: zero only xt's pad border (replaces 8.6MB memset) ----------
// units of 8 shorts (16B). Per batch: rows {0,129}: 2*130*8 = 2080; cols {0,129}: 2*128*8 = 2048.
__global__ void k_zero_pad(unsigned short* __restrict__ xt) {
    int i = blockIdx.x * 256 + threadIdx.x;     // over BB*4128
    if (i >= BB * 4128) return;
    int b = i / 4128, r = i - b * 4128;
    size_t base;
    if (r < 2080) {
        int row = r / 1040;              // 0 -> hp 0, 1 -> hp 129
        int rr  = r - row * 1040;        // over 130*8
        int wp = rr >> 3, c8 = rr & 7;
        int hp = row ? (HP - 1) : 0;
        base = (((size_t)b * HP + hp) * WP + wp) * 64 + c8 * 8;
    } else {
        int r2 = r - 2080;               // over 2*128*8
        int col = r2 >> 10;              // 0 -> wp 0, 1 -> wp 129
        int rr  = r2 & 1023;
        int hp = (rr >> 3) + 1, c8 = rr & 7;
        int wp = col ? (WP - 1) : 0;
        base = (((size_t)b * HP + hp) * WP + wp) * 64 + c8 * 8;
    }
    *reinterpret_cast<int4*>(xt + base) = make_int4(0, 0, 0, 0);
}

// ---------------- kernel 0b: x NCHW fp32 -> xt NHWC bf16 (interior rows/cols) ----------
__global__ __launch_bounds__(256) void k_nhwc(const float* __restrict__ x,
                                              unsigned short* __restrict__ xt) {
    __shared__ float tile[64][129];
    int blk = blockIdx.x;          // b*128 + h
    int b = blk >> 7, h = blk & 127;
    int t = threadIdx.x;
    const float* xb = x + ((size_t)b * CC) * HW + h * WW;
    #pragma unroll
    for (int i = 0; i < 32; ++i) {
        int idx = i * 256 + t;             // over 64ci*128w
        int ci = idx >> 7, w = idx & 127;
        tile[ci][w] = xb[(size_t)ci * HW + w];
    }
    __syncthreads();
    unsigned short* xtb = xt + (((size_t)b * HP + (h + 1)) * WP + 1) * 64;
    #pragma unroll
    for (int i = 0; i < 32; ++i) {
        int idx = i * 256 + t;
        int w = idx >> 6, ci = idx & 63;
        xtb[(size_t)w * 64 + ci] = f2bf(tile[ci][w]);
    }
}

// ---------------- kernel 1: offset(18)+mask(9) conv via MFMA on NHWC xt ----------------
// block: 64 px (half h-row) x 32 co; 8 waves, each a 16px x 16co quadrant; no LDS/barriers.
__global__ __launch_bounds__(512) void k_om_mfma(
    const unsigned short* __restrict__ xt, const unsigned short* __restrict__ wttB,
    const float* __restrict__ b27,
    float* __restrict__ offs, float* __restrict__ mask)
{
    int blk = blockIdx.x;            // b*256 + h*2 + wblk
    int wblk = blk & 1;
    int h = (blk >> 1) & 127;
    int b = blk >> 8;
    int w0 = wblk * 64;
    int t = threadIdx.x;
    int ln = t & 63, wid = t >> 6;
    int ln15 = ln & 15, lhi = ln >> 4;
    int pxg = wid >> 1, coh = wid & 1;

    const unsigned short* xtb = xt + (size_t)b * HP * WP * 64;
    int px = pxg * 16 + ln15;

    f32x4 acc;
    acc[0] = 0.f; acc[1] = 0.f; acc[2] = 0.f; acc[3] = 0.f;

    #pragma unroll
    for (int n = 0; n < NPT; ++n) {
        int kh = n / 3, kw = n - kh * 3;
        // A row for tap n: xt[h+kh][w0+px+kw][ci]
        const unsigned short* arow = xtb + ((size_t)(h + kh) * WP + (w0 + px + kw)) * 64;
        #pragma unroll
        for (int s2 = 0; s2 < 2; ++s2) {
            bf16x8 af = *reinterpret_cast<const bf16x8*>(arow + s2 * 32 + lhi * 8);
            bf16x8 bf = *reinterpret_cast<const bf16x8*>(
                wttB + ((((n * 2 + s2) * 4 + lhi) * 32) + coh * 16 + ln15) * 8);
            acc = __builtin_amdgcn_mfma_f32_16x16x32_bf16(af, bf, acc, 0, 0, 0);
        }
    }

    // epilogue: lane holds co = coh*16+ln15 (col), px rows = pxg*16 + lhi*4 + r
    int co = coh * 16 + ln15;
    float bias = b27[co];
    int prow = pxg * 16 + lhi * 4;
    if (co < 18) {
        float4 v;
        v.x = acc[0] + bias; v.y = acc[1] + bias;
        v.z = acc[2] + bias; v.w = acc[3] + bias;
        *reinterpret_cast<float4*>(&offs[((size_t)b * 18 + co) * HW + h * WW + w0 + prow]) = v;
    } else if (co < 27) {
        float4 v;
        v.x = 1.f / (1.f + expf(-(acc[0] + bias)));
        v.y = 1.f / (1.f + expf(-(acc[1] + bias)));
        v.z = 1.f / (1.f + expf(-(acc[2] + bias)));
        v.w = 1.f / (1.f + expf(-(acc[3] + bias)));
        *reinterpret_cast<float4*>(&mask[((size_t)b * 9 + (co - 18)) * HW + h * WW + w0 + prow]) = v;
    }
}

// ---------------- kernel 2: fused bilinear sampling (NHWC bf16) + MFMA GEMM ----------------
// block: 64 px (one h-row chunk) x 64 co, K=576 as 9 n-groups of 64 ci. 512 threads.
// sampling lanes: px = t>>3, cig = t&7 (8 ci-vec chunks) -> coalesced 128B xt vectors.
__global__ __launch_bounds__(512, 4) void k_deform_mfma(
    const unsigned short* __restrict__ xt, const float* __restrict__ offs,
    const float* __restrict__ mask, const unsigned short* __restrict__ wtt,
    float* __restrict__ out)
{
    __shared__ int s_geo[576 * 8];          // [n*64+px][a0 a1 a2 a3 w0 w1 w2 w3] 18432 B
    __shared__ unsigned int s_xoff[2048];   // [64 px][64 ci] bf16, XOR-swizzled, 8192 B

    // XCD-chunked swizzle: 1024 blocks, 8 XCDs -> each XCD gets contiguous 128
    int blk0 = blockIdx.x;
    int blk = (blk0 & 7) * 128 + (blk0 >> 3);
    int wblk = blk & 1;
    int h = (blk >> 1) & 127;
    int b = blk >> 8;
    int w0 = wblk * 64;
    int t = threadIdx.x;
    int ln = t & 63, wid = t >> 6;          // 8 waves
    int ln15 = ln & 15, lhi = ln >> 4;

    // ---- phase G: geometry for 9 n x 64 px ----
    for (int idx = t; idx < NPT * 64; idx += 512) {
        int n = idx >> 6, px = idx & 63;
        int w = w0 + px;
        float ox = offs[((size_t)b * 18 + n) * HW + h * WW + w];
        float oy = offs[((size_t)b * 18 + 9 + n) * HW + h * WW + w];
        float mk = mask[((size_t)b * 9 + n) * HW + h * WW + w];
        float pxf = ox + (float)(n / 3 - 1) + (float)(h + 1);
        float pyf = oy + (float)(n % 3 - 1) + (float)(w + 1);
        float fx = floorf(pxf), fy = floorf(pyf);
        int qxlt = (int)fminf(fmaxf(fx, 0.f), 129.f);
        int qylt = (int)fminf(fmaxf(fy, 0.f), 129.f);
        int qxrb = (int)fminf(fmaxf(fx + 1.f, 0.f), 129.f);
        int qyrb = (int)fminf(fmaxf(fy + 1.f, 0.f), 129.f);
        float pxc = fminf(fmaxf(pxf, 0.f), 129.f);
        float pyc = fminf(fmaxf(pyf, 0.f), 129.f);
        float ax = 1.f + (float)qxlt - pxc;
        float bx = 1.f - ((float)qxrb - pxc);
        float ay = 1.f + (float)qylt - pyc;
        float by = 1.f - ((float)qyrb - pyc);
        // pads in xt are real zeros -> no validity masking needed (matches reference xp)
        int* g = &s_geo[idx * 8];
        g[0] = (qxlt * WP + qylt) * 64;
        g[1] = (qxrb * WP + qyrb) * 64;
        g[2] = (qxlt * WP + qyrb) * 64;
        g[3] = (qxrb * WP + qylt) * 64;
        reinterpret_cast<float*>(g)[4] = ax * ay * mk;
        reinterpret_cast<float*>(g)[5] = bx * by * mk;
        reinterpret_cast<float*>(g)[6] = ax * by * mk;
        reinterpret_cast<float*>(g)[7] = bx * ay * mk;
    }
    __syncthreads();

    f32x4 acc[2];
    #pragma unroll
    for (int g = 0; g < 2; ++g) {
        acc[g][0] = 0.f; acc[g][1] = 0.f; acc[g][2] = 0.f; acc[g][3] = 0.f;
    }

    const unsigned short* wrow = wtt + (size_t)((wid & 3) * 16 + ln15) * 576;
    const unsigned short* xtb = xt + (size_t)b * HP * WP * 64;
    int px_s = t >> 3;          // sampling: 64 px
    int cig_s = t & 7;          // 8-ci-vec chunk (8 ci each)
    char* xoff_base = reinterpret_cast<char*>(s_xoff);
    int ghalf = wid >> 2;       // px-half for MFMA role

    for (int n = 0; n < NPT; ++n) {
        // B fragments for this n (global, L2-hot; consumed after the barrier)
        bf16x8 bf0 = *reinterpret_cast<const bf16x8*>(wrow + n * 64 + lhi * 8);
        bf16x8 bf1 = *reinterpret_cast<const bf16x8*>(wrow + n * 64 + 32 + lhi * 8);

        // ---- sampling: 8 ci (one bf16x8 per corner) for this thread's px ----
        const int* gp = &s_geo[(n * 64 + px_s) * 8];
        int a0 = gp[0], a1 = gp[1], a2 = gp[2], a3 = gp[3];
        float glt = reinterpret_cast<const float*>(gp)[4];
        float grb = reinterpret_cast<const float*>(gp)[5];
        float glb = reinterpret_cast<const float*>(gp)[6];
        float grt = reinterpret_cast<const float*>(gp)[7];

        int coff = cig_s * 8;
        bf16x8 c0 = *reinterpret_cast<const bf16x8*>(xtb + a0 + coff);
        bf16x8 c1 = *reinterpret_cast<const bf16x8*>(xtb + a1 + coff);
        bf16x8 c2 = *reinterpret_cast<const bf16x8*>(xtb + a2 + coff);
        bf16x8 c3 = *reinterpret_cast<const bf16x8*>(xtb + a3 + coff);

        unsigned int pk[4];
        #pragma unroll
        for (int i = 0; i < 4; ++i) {
            float va = glt * bf2f((unsigned short)c0[2*i])   + grb * bf2f((unsigned short)c1[2*i])
                     + glb * bf2f((unsigned short)c2[2*i])   + grt * bf2f((unsigned short)c3[2*i]);
            float vb = glt * bf2f((unsigned short)c0[2*i+1]) + grb * bf2f((unsigned short)c1[2*i+1])
                     + glb * bf2f((unsigned short)c2[2*i+1]) + grt * bf2f((unsigned short)c3[2*i+1]);
            pk[i] = (unsigned int)f2bf(va) | ((unsigned int)f2bf(vb) << 16);
        }
        {
            char* base = xoff_base + px_s * 128;
            int sw = (px_s & 7) << 4;
            *reinterpret_cast<int4*>(base + ((cig_s * 16) ^ sw)) = *reinterpret_cast<int4*>(&pk[0]);
        }
        __syncthreads();

        // ---- MFMA: 2 k-steps x 2 px-groups per wave ----
        #pragma unroll
        for (int s2 = 0; s2 < 2; ++s2) {
            bf16x8 bfr = s2 ? bf1 : bf0;
            #pragma unroll
            for (int g = 0; g < 2; ++g) {
                int row = (ghalf * 2 + g) * 16 + ln15;
                int cb2 = (s2 * 32 + lhi * 8) * 2;
                bf16x8 af = *reinterpret_cast<const bf16x8*>(
                    xoff_base + row * 128 + (cb2 ^ ((row & 7) << 4)));
                acc[g] = __builtin_amdgcn_mfma_f32_16x16x32_bf16(af, bfr, acc[g], 0, 0, 0);
            }
        }
        __syncthreads();
    }

    // ---- epilogue: lane holds co = (wid&3)*16 + ln15, px = (ghalf*2+g)*16 + lhi*4 + r ----
    int co = (wid & 3) * 16 + ln15;
    float* orow = out + ((size_t)b * CC + co) * HW + h * WW + w0;
    #pragma unroll
    for (int g = 0; g < 2; ++g) {
        *reinterpret_cast<float4*>(orow + (ghalf * 2 + g) * 16 + lhi * 4) =
            *reinterpret_cast<float4*>(&acc[g]);
    }
}

extern "C" void kernel_launch(void* const* d_in, const int* in_sizes, int n_in,
                              void* d_out, int out_size, void* d_ws, size_t ws_size,
                              hipStream_t stream) {
    const float* x  = (const float*)d_in[0];
    const float* pw = (const float*)d_in[1];
    const float* pb = (const float*)d_in[2];
    const float* mw = (const float*)d_in[3];
    const float* mb = (const float*)d_in[4];
    const float* cw = (const float*)d_in[5];
    float* out = (float*)d_out;

    // ws layout (bytes, 256-aligned sections):
    char* wsc = (char*)d_ws;
    unsigned short* xt  = (unsigned short*)wsc;                         // 4*130*130*64 bf16 = 8,652,800 B
    size_t off = ((size_t)BB * HP * WP * 64 * 2 + 255) & ~(size_t)255;
    float* offs  = (float*)(wsc + off);                                 // 4*18*16384 f32
    off += (size_t)BB * 18 * HW * 4;
    float* maskp = (float*)(wsc + off);                                 // 4*9*16384 f32
    off += (size_t)BB * 9 * HW * 4;
    unsigned short* wtt = (unsigned short*)(wsc + off);                 // 64*576 bf16
    off += (size_t)64 * 576 * 2;
    unsigned short* wttB = (unsigned short*)(wsc + off);                // 18432 bf16
    off += (size_t)18432 * 2 + 128;
    float* b27 = (float*)(wsc + ((off + 255) & ~(size_t)255));          // 32 f32

    hipLaunchKernelGGL(k_zero_pad, dim3((BB * 4128 + 255) / 256), dim3(256), 0, stream, xt);
    hipLaunchKernelGGL(k_prep_w, dim3((64 * 576 + 255) / 256), dim3(256), 0, stream, cw, wtt);
    hipLaunchKernelGGL(k_prep_w27, dim3((18432 + 32 + 255) / 256), dim3(256), 0, stream,
                       pw, pb, mw, mb, wttB, b27);
    hipLaunchKernelGGL(k_nhwc, dim3(BB * HH), dim3(256), 0, stream, x, xt);
    hipLaunchKernelGGL(k_om_mfma, dim3(BB * HH * 2), dim3(512), 0, stream,
                       xt, wttB, b27, offs, maskp);
    hipLaunchKernelGGL(k_deform_mfma, dim3(BB * HH * 2), dim3(512), 0, stream,
                       xt, offs, maskp, wtt, out);
}

// Round 8
// 67.104 us; speedup vs baseline: 7.6510x; 1.1304x over previous
//
#include <hip/hip_runtime.h>
#include <hip/hip_bf16.h>
#include <math.h>

#define BB 4
#define CC 64
#define HH 128
#define WW 128
#define NPT 9
#define HW (HH*WW)
#define HP 130
#define WP 130

typedef __attribute__((ext_vector_type(8))) short bf16x8;
typedef __attribute__((ext_vector_type(4))) float f32x4;

static __device__ __forceinline__ unsigned short f2bf(float f) {
    __hip_bfloat16 h = __float2bfloat16(f);
    return *reinterpret_cast<unsigned short*>(&h);
}
static __device__ __forceinline__ float bf2f(unsigned short u) {
    return __uint_as_float(((unsigned int)u) << 16);
}

// ---------------- kernel 0: all prep (wtt pack, wttB pack, b27, xt pad zero) ------------
// flat i: [0,36864) wtt | [36864,55296) wttB | [55296,55328) b27 | [55328,71840) pad-zero
__global__ void k_prep(const float* __restrict__ cw,
                       const float* __restrict__ pw, const float* __restrict__ pb,
                       const float* __restrict__ mw, const float* __restrict__ mb,
                       unsigned short* __restrict__ wtt, unsigned short* __restrict__ wttB,
                       float* __restrict__ b27, unsigned short* __restrict__ xt) {
    int i = blockIdx.x * 256 + threadIdx.x;
    if (i < 36864) {
        int co = i / 576, k = i - co * 576;
        int ci = k / 9, n = k - ci * 9;
        wtt[co * 576 + n * 64 + ci] = f2bf(cw[i]);
    } else if (i < 55296) {
        int q = i - 36864;
        int j   = q & 7;
        int co  = (q >> 3) & 31;
        int lhi = (q >> 8) & 3;
        int s2  = (q >> 10) & 1;
        int n   = q >> 11;
        int ci  = s2 * 32 + lhi * 8 + j;
        float v = 0.f;
        if (co < 18) v = pw[(co * 64 + ci) * 9 + n];
        else if (co < 27) v = mw[((co - 18) * 64 + ci) * 9 + n];
        wttB[q] = f2bf(v);
    } else if (i < 55328) {
        int co = i - 55296;
        b27[co] = (co < 18) ? pb[co] : (co < 27 ? mb[co - 18] : 0.f);
    } else if (i < 55328 + BB * 4128) {
        int p = i - 55328;
        int b = p / 4128, r = p - b * 4128;
        size_t base;
        if (r < 2080) {
            int row = r / 1040;
            int rr  = r - row * 1040;
            int wp = rr >> 3, c8 = rr & 7;
            int hp = row ? (HP - 1) : 0;
            base = (((size_t)b * HP + hp) * WP + wp) * 64 + c8 * 8;
        } else {
            int r2 = r - 2080;
            int col = r2 >> 10;
            int rr  = r2 & 1023;
            int hp = (rr >> 3) + 1, c8 = rr & 7;
            int wp = col ? (WP - 1) : 0;
            base = (((size_t)b * HP + hp) * WP + wp) * 64 + c8 * 8;
        }
        *reinterpret_cast<int4*>(xt + base) = make_int4(0, 0, 0, 0);
    }
}

// ---------------- kernel 0b: x NCHW fp32 -> xt NHWC bf16 (interior) ----------
__global__ __launch_bounds__(256) void k_nhwc(const float* __restrict__ x,
                                              unsigned short* __restrict__ xt) {
    __shared__ float tile[64][129];
    int blk = blockIdx.x;          // b*128 + h
    int b = blk >> 7, h = blk & 127;
    int t = threadIdx.x;
    const float* xb = x + ((size_t)b * CC) * HW + h * WW;
    #pragma unroll
    for (int i = 0; i < 32; ++i) {
        int idx = i * 256 + t;             // over 64ci*128w
        int ci = idx >> 7, w = idx & 127;
        tile[ci][w] = xb[(size_t)ci * HW + w];
    }
    __syncthreads();
    unsigned short* xtb = xt + (((size_t)b * HP + (h + 1)) * WP + 1) * 64;
    #pragma unroll
    for (int i = 0; i < 32; ++i) {
        int idx = i * 256 + t;
        int w = idx >> 6, ci = idx & 63;
        xtb[(size_t)w * 64 + ci] = f2bf(tile[ci][w]);
    }
}

// ---------------- fused kernel: offset/mask MFMA -> LDS -> bilinear sampling + MFMA GEMM ----
// block: 64 px (half h-row) x 64 co out, 512 threads (8 waves).
#define OMS 68   // s_om row stride (floats): conflict-free + 16B-aligned rows
__global__ __launch_bounds__(512, 4) void k_fused(
    const unsigned short* __restrict__ xt, const unsigned short* __restrict__ wttB,
    const float* __restrict__ b27, const unsigned short* __restrict__ wtt,
    float* __restrict__ out)
{
    __shared__ float s_om[27 * OMS];        // offsets(18) + mask(9) for this block's 64 px, 7344 B
    __shared__ int s_geo[576 * 8];          // [n*64+px][a0 a1 a2 a3 w0 w1 w2 w3] 18432 B
    __shared__ unsigned int s_xoff[2048];   // [64 px][64 ci] bf16, XOR-swizzled, 8192 B

    // XCD-chunked swizzle: 1024 blocks, 8 XCDs -> each XCD gets contiguous 128
    int blk0 = blockIdx.x;
    int blk = (blk0 & 7) * 128 + (blk0 >> 3);
    int wblk = blk & 1;
    int h = (blk >> 1) & 127;
    int b = blk >> 8;
    int w0 = wblk * 64;
    int t = threadIdx.x;
    int ln = t & 63, wid = t >> 6;          // 8 waves
    int ln15 = ln & 15, lhi = ln >> 4;

    const unsigned short* xtb = xt + (size_t)b * HP * WP * 64;

    // ---- phase A: offset/mask conv via MFMA, results -> s_om ----
    {
        int pxg = wid >> 1, coh = wid & 1;     // wave quadrant: 16 px x 16 co
        int px = pxg * 16 + ln15;
        f32x4 acc;
        acc[0] = 0.f; acc[1] = 0.f; acc[2] = 0.f; acc[3] = 0.f;
        #pragma unroll
        for (int n = 0; n < NPT; ++n) {
            int kh = n / 3, kw = n - kh * 3;
            const unsigned short* arow = xtb + ((size_t)(h + kh) * WP + (w0 + px + kw)) * 64;
            #pragma unroll
            for (int s2 = 0; s2 < 2; ++s2) {
                bf16x8 af = *reinterpret_cast<const bf16x8*>(arow + s2 * 32 + lhi * 8);
                bf16x8 bf = *reinterpret_cast<const bf16x8*>(
                    wttB + ((((n * 2 + s2) * 4 + lhi) * 32) + coh * 16 + ln15) * 8);
                acc = __builtin_amdgcn_mfma_f32_16x16x32_bf16(af, bf, acc, 0, 0, 0);
            }
        }
        int co = coh * 16 + ln15;
        int prow = pxg * 16 + lhi * 4;
        if (co < 27) {
            float bias = b27[co];
            float4 v;
            v.x = acc[0] + bias; v.y = acc[1] + bias;
            v.z = acc[2] + bias; v.w = acc[3] + bias;
            if (co >= 18) {
                v.x = 1.f / (1.f + expf(-v.x));
                v.y = 1.f / (1.f + expf(-v.y));
                v.z = 1.f / (1.f + expf(-v.z));
                v.w = 1.f / (1.f + expf(-v.w));
            }
            *reinterpret_cast<float4*>(&s_om[co * OMS + prow]) = v;
        }
    }
    __syncthreads();

    // ---- phase G: geometry for 9 n x 64 px (from s_om) ----
    for (int idx = t; idx < NPT * 64; idx += 512) {
        int n = idx >> 6, px = idx & 63;
        float ox = s_om[n * OMS + px];
        float oy = s_om[(9 + n) * OMS + px];
        float mk = s_om[(18 + n) * OMS + px];
        float pxf = ox + (float)(n / 3 - 1) + (float)(h + 1);
        float pyf = oy + (float)(n % 3 - 1) + (float)(w0 + px + 1);
        float fx = floorf(pxf), fy = floorf(pyf);
        int qxlt = (int)fminf(fmaxf(fx, 0.f), 129.f);
        int qylt = (int)fminf(fmaxf(fy, 0.f), 129.f);
        int qxrb = (int)fminf(fmaxf(fx + 1.f, 0.f), 129.f);
        int qyrb = (int)fminf(fmaxf(fy + 1.f, 0.f), 129.f);
        float pxc = fminf(fmaxf(pxf, 0.f), 129.f);
        float pyc = fminf(fmaxf(pyf, 0.f), 129.f);
        float ax = 1.f + (float)qxlt - pxc;
        float bx = 1.f - ((float)qxrb - pxc);
        float ay = 1.f + (float)qylt - pyc;
        float by = 1.f - ((float)qyrb - pyc);
        // pads in xt are real zeros -> no validity masking needed (matches reference xp)
        int* g = &s_geo[idx * 8];
        g[0] = (qxlt * WP + qylt) * 64;
        g[1] = (qxrb * WP + qyrb) * 64;
        g[2] = (qxlt * WP + qyrb) * 64;
        g[3] = (qxrb * WP + qylt) * 64;
        reinterpret_cast<float*>(g)[4] = ax * ay * mk;
        reinterpret_cast<float*>(g)[5] = bx * by * mk;
        reinterpret_cast<float*>(g)[6] = ax * by * mk;
        reinterpret_cast<float*>(g)[7] = bx * ay * mk;
    }
    __syncthreads();

    // ---- phase D: deformable sampling + GEMM ----
    f32x4 acc[2];
    #pragma unroll
    for (int g = 0; g < 2; ++g) {
        acc[g][0] = 0.f; acc[g][1] = 0.f; acc[g][2] = 0.f; acc[g][3] = 0.f;
    }

    const unsigned short* wrow = wtt + (size_t)((wid & 3) * 16 + ln15) * 576;
    int px_s = t >> 3;          // sampling: 64 px
    int cig_s = t & 7;          // 8-ci-vec chunk (8 ci each)
    char* xoff_base = reinterpret_cast<char*>(s_xoff);
    int ghalf = wid >> 2;       // px-half for MFMA role

    for (int n = 0; n < NPT; ++n) {
        bf16x8 bf0 = *reinterpret_cast<const bf16x8*>(wrow + n * 64 + lhi * 8);
        bf16x8 bf1 = *reinterpret_cast<const bf16x8*>(wrow + n * 64 + 32 + lhi * 8);

        const int* gp = &s_geo[(n * 64 + px_s) * 8];
        int a0 = gp[0], a1 = gp[1], a2 = gp[2], a3 = gp[3];
        float glt = reinterpret_cast<const float*>(gp)[4];
        float grb = reinterpret_cast<const float*>(gp)[5];
        float glb = reinterpret_cast<const float*>(gp)[6];
        float grt = reinterpret_cast<const float*>(gp)[7];

        int coff = cig_s * 8;
        bf16x8 c0 = *reinterpret_cast<const bf16x8*>(xtb + a0 + coff);
        bf16x8 c1 = *reinterpret_cast<const bf16x8*>(xtb + a1 + coff);
        bf16x8 c2 = *reinterpret_cast<const bf16x8*>(xtb + a2 + coff);
        bf16x8 c3 = *reinterpret_cast<const bf16x8*>(xtb + a3 + coff);

        unsigned int pk[4];
        #pragma unroll
        for (int i = 0; i < 4; ++i) {
            float va = glt * bf2f((unsigned short)c0[2*i])   + grb * bf2f((unsigned short)c1[2*i])
                     + glb * bf2f((unsigned short)c2[2*i])   + grt * bf2f((unsigned short)c3[2*i]);
            float vb = glt * bf2f((unsigned short)c0[2*i+1]) + grb * bf2f((unsigned short)c1[2*i+1])
                     + glb * bf2f((unsigned short)c2[2*i+1]) + grt * bf2f((unsigned short)c3[2*i+1]);
            pk[i] = (unsigned int)f2bf(va) | ((unsigned int)f2bf(vb) << 16);
        }
        {
            char* base = xoff_base + px_s * 128;
            int sw = (px_s & 7) << 4;
            *reinterpret_cast<int4*>(base + ((cig_s * 16) ^ sw)) = *reinterpret_cast<int4*>(&pk[0]);
        }
        __syncthreads();

        #pragma unroll
        for (int s2 = 0; s2 < 2; ++s2) {
            bf16x8 bfr = s2 ? bf1 : bf0;
            #pragma unroll
            for (int g = 0; g < 2; ++g) {
                int row = (ghalf * 2 + g) * 16 + ln15;
                int cb2 = (s2 * 32 + lhi * 8) * 2;
                bf16x8 af = *reinterpret_cast<const bf16x8*>(
                    xoff_base + row * 128 + (cb2 ^ ((row & 7) << 4)));
                acc[g] = __builtin_amdgcn_mfma_f32_16x16x32_bf16(af, bfr, acc[g], 0, 0, 0);
            }
        }
        __syncthreads();
    }

    // ---- epilogue: lane holds co = (wid&3)*16 + ln15, px = (ghalf*2+g)*16 + lhi*4 + r ----
    int co = (wid & 3) * 16 + ln15;
    float* orow = out + ((size_t)b * CC + co) * HW + h * WW + w0;
    #pragma unroll
    for (int g = 0; g < 2; ++g) {
        *reinterpret_cast<float4*>(orow + (ghalf * 2 + g) * 16 + lhi * 4) =
            *reinterpret_cast<float4*>(&acc[g]);
    }
}

extern "C" void kernel_launch(void* const* d_in, const int* in_sizes, int n_in,
                              void* d_out, int out_size, void* d_ws, size_t ws_size,
                              hipStream_t stream) {
    const float* x  = (const float*)d_in[0];
    const float* pw = (const float*)d_in[1];
    const float* pb = (const float*)d_in[2];
    const float* mw = (const float*)d_in[3];
    const float* mb = (const float*)d_in[4];
    const float* cw = (const float*)d_in[5];
    float* out = (float*)d_out;

    // ws layout (bytes, 256-aligned sections):
    char* wsc = (char*)d_ws;
    unsigned short* xt  = (unsigned short*)wsc;                         // 4*130*130*64 bf16
    size_t off = ((size_t)BB * HP * WP * 64 * 2 + 255) & ~(size_t)255;
    unsigned short* wtt = (unsigned short*)(wsc + off);                 // 64*576 bf16
    off += (size_t)64 * 576 * 2;
    unsigned short* wttB = (unsigned short*)(wsc + off);                // 18432 bf16
    off += (size_t)18432 * 2;
    float* b27 = (float*)(wsc + ((off + 255) & ~(size_t)255));          // 32 f32

    int prep_items = 36864 + 18432 + 32 + BB * 4128;
    hipLaunchKernelGGL(k_prep, dim3((prep_items + 255) / 256), dim3(256), 0, stream,
                       cw, pw, pb, mw, mb, wtt, wttB, b27, xt);
    hipLaunchKernelGGL(k_nhwc, dim3(BB * HH), dim3(256), 0, stream, x, xt);
    hipLaunchKernelGGL(k_fused, dim3(BB * HH * 2), dim3(512), 0, stream,
                       xt, wttB, b27, wtt, out);
}

// Round 9
// 45.498 us; speedup vs baseline: 11.2842x; 1.4749x over previous
//
#include <hip/hip_runtime.h>
#include <hip/hip_bf16.h>
#include <math.h>

#define BB 4
#define CC 64
#define HH 128
#define WW 128
#define NPT 9
#define HW (HH*WW)
#define HP 130
#define WP 130

typedef __attribute__((ext_vector_type(8))) short bf16x8;
typedef __attribute__((ext_vector_type(4))) float f32x4;

static __device__ __forceinline__ unsigned short f2bf(float f) {
    __hip_bfloat16 h = __float2bfloat16(f);
    return *reinterpret_cast<unsigned short*>(&h);
}
static __device__ __forceinline__ float bf2f(unsigned short u) {
    return __uint_as_float(((unsigned int)u) << 16);
}

// ---------------- kernel 0: all prep (wtt frag-pack, wttB pack, b27, xt pad zero) --------
// flat i: [0,36864) wtt | [36864,55296) wttB | [55296,55328) b27 | [55328,+BB*4128) pad-zero
// wtt fragment-major: [cot(4)][n(9)][s2(2)][lhi(4)][ln15(16)][j(8)], co=cot*16+ln15, ci=s2*32+lhi*8+j
__global__ void k_prep(const float* __restrict__ cw,
                       const float* __restrict__ pw, const float* __restrict__ pb,
                       const float* __restrict__ mw, const float* __restrict__ mb,
                       unsigned short* __restrict__ wtt, unsigned short* __restrict__ wttB,
                       float* __restrict__ b27, unsigned short* __restrict__ xt) {
    int i = blockIdx.x * 256 + threadIdx.x;
    if (i < 36864) {
        int cot = i / 9216;
        int rem = i - cot * 9216;
        int n   = rem >> 10;
        int s2  = (rem >> 9) & 1;
        int lhi = (rem >> 7) & 3;
        int l15 = (rem >> 3) & 15;
        int j   = i & 7;
        int co = cot * 16 + l15;
        int ci = s2 * 32 + lhi * 8 + j;
        wtt[i] = f2bf(cw[(co * 64 + ci) * 9 + n]);
    } else if (i < 55296) {
        int q = i - 36864;
        int j   = q & 7;
        int co  = (q >> 3) & 31;
        int lhi = (q >> 8) & 3;
        int s2  = (q >> 10) & 1;
        int n   = q >> 11;
        int ci  = s2 * 32 + lhi * 8 + j;
        float v = 0.f;
        if (co < 18) v = pw[(co * 64 + ci) * 9 + n];
        else if (co < 27) v = mw[((co - 18) * 64 + ci) * 9 + n];
        wttB[q] = f2bf(v);
    } else if (i < 55328) {
        int co = i - 55296;
        b27[co] = (co < 18) ? pb[co] : (co < 27 ? mb[co - 18] : 0.f);
    } else if (i < 55328 + BB * 4128) {
        int p = i - 55328;
        int b = p / 4128, r = p - b * 4128;
        size_t base;
        if (r < 2080) {
            int row = r / 1040;
            int rr  = r - row * 1040;
            int wp = rr >> 3, c8 = rr & 7;
            int hp = row ? (HP - 1) : 0;
            base = (((size_t)b * HP + hp) * WP + wp) * 64 + c8 * 8;
        } else {
            int r2 = r - 2080;
            int col = r2 >> 10;
            int rr  = r2 & 1023;
            int hp = (rr >> 3) + 1, c8 = rr & 7;
            int wp = col ? (WP - 1) : 0;
            base = (((size_t)b * HP + hp) * WP + wp) * 64 + c8 * 8;
        }
        *reinterpret_cast<int4*>(xt + base) = make_int4(0, 0, 0, 0);
    }
}

// ---------------- kernel 0b: x NCHW fp32 -> xt NHWC bf16 (interior) ----------
__global__ __launch_bounds__(256) void k_nhwc(const float* __restrict__ x,
                                              unsigned short* __restrict__ xt) {
    __shared__ float tile[64][129];
    int blk = blockIdx.x;          // b*128 + h
    int b = blk >> 7, h = blk & 127;
    int t = threadIdx.x;
    const float* xb = x + ((size_t)b * CC) * HW + h * WW;
    #pragma unroll
    for (int i = 0; i < 32; ++i) {
        int idx = i * 256 + t;             // over 64ci*128w
        int ci = idx >> 7, w = idx & 127;
        tile[ci][w] = xb[(size_t)ci * HW + w];
    }
    __syncthreads();
    unsigned short* xtb = xt + (((size_t)b * HP + (h + 1)) * WP + 1) * 64;
    #pragma unroll
    for (int i = 0; i < 32; ++i) {
        int idx = i * 256 + t;
        int w = idx >> 6, ci = idx & 63;
        xtb[(size_t)w * 64 + ci] = f2bf(tile[ci][w]);
    }
}

// ---------------- fused kernel ----------------
// block: 64 px (half h-row) x 64 co out, 512 threads (8 waves).
#define OMS 68    // s_om row stride (floats)
#define NCX 198   // 3 rows x 66 cols of A-stage chunks

union SmemU {
    struct { int geo[576 * 8]; unsigned int xoff[2048]; } d;   // 26624 B (phases G,D)
    unsigned short astage[NCX * 64];                           // 25344 B (phase A)
};

__global__ __launch_bounds__(512, 4) void k_fused(
    const unsigned short* __restrict__ xt, const unsigned short* __restrict__ wttB,
    const float* __restrict__ b27, const unsigned short* __restrict__ wtt,
    float* __restrict__ out)
{
    __shared__ SmemU su;
    __shared__ float s_om[27 * OMS];

    // XCD-chunked swizzle: 1024 blocks, 8 XCDs
    int blk0 = blockIdx.x;
    int blk = (blk0 & 7) * 128 + (blk0 >> 3);
    int wblk = blk & 1;
    int h = (blk >> 1) & 127;
    int b = blk >> 8;
    int w0 = wblk * 64;
    int t = threadIdx.x;
    int ln = t & 63, wid = t >> 6;          // 8 waves
    int ln15 = ln & 15, lhi = ln >> 4;

    const unsigned short* xtb = xt + (size_t)b * HP * WP * 64;
    char* astage_c = reinterpret_cast<char*>(su.astage);

    // ---- phase S: stage A-tile rows h..h+2, cols w0..w0+65, swizzled ----
    for (int uu = t; uu < NCX * 8; uu += 512) {
        int cx = uu >> 3, o16 = uu & 7;
        int r = cx / 66, c = cx - r * 66;
        const unsigned short* src = xtb + ((size_t)(h + r) * WP + (w0 + c)) * 64 + o16 * 8;
        int4 v = *reinterpret_cast<const int4*>(src);
        *reinterpret_cast<int4*>(astage_c + cx * 128 + ((o16 ^ (cx & 7)) << 4)) = v;
    }
    __syncthreads();

    // ---- phase A: offset/mask conv via MFMA (A from LDS, B pipelined), -> s_om ----
    {
        int pxg = wid >> 1, coh = wid & 1;     // wave quadrant: 16 px x 16 co
        int px = pxg * 16 + ln15;
        f32x4 acc;
        acc[0] = 0.f; acc[1] = 0.f; acc[2] = 0.f; acc[3] = 0.f;
        const unsigned short* wB = wttB + (size_t)(coh * 16 + ln15) * 8 + lhi * 256;
        bf16x8 bfc = *reinterpret_cast<const bf16x8*>(wB);       // ns = 0
        #pragma unroll
        for (int ns = 0; ns < 18; ++ns) {
            bf16x8 bfn = bfc;
            if (ns < 17)
                bfn = *reinterpret_cast<const bf16x8*>(wB + (size_t)(ns + 1) * 1024);
            int n = ns >> 1, s2 = ns & 1;
            int kh = n / 3, kw = n - kh * 3;
            int cx = kh * 66 + px + kw;
            int o16 = s2 * 4 + lhi;
            bf16x8 af = *reinterpret_cast<const bf16x8*>(
                astage_c + cx * 128 + ((o16 ^ (cx & 7)) << 4));
            acc = __builtin_amdgcn_mfma_f32_16x16x32_bf16(af, bfc, acc, 0, 0, 0);
            bfc = bfn;
        }
        int co = coh * 16 + ln15;
        int prow = pxg * 16 + lhi * 4;
        if (co < 27) {
            float bias = b27[co];
            float4 v;
            v.x = acc[0] + bias; v.y = acc[1] + bias;
            v.z = acc[2] + bias; v.w = acc[3] + bias;
            if (co >= 18) {
                v.x = 1.f / (1.f + expf(-v.x));
                v.y = 1.f / (1.f + expf(-v.y));
                v.z = 1.f / (1.f + expf(-v.z));
                v.w = 1.f / (1.f + expf(-v.w));
            }
            *reinterpret_cast<float4*>(&s_om[co * OMS + prow]) = v;
        }
    }
    __syncthreads();

    int* s_geo = su.d.geo;

    // ---- phase G: geometry for 9 n x 64 px (overwrites astage region) ----
    for (int idx = t; idx < NPT * 64; idx += 512) {
        int n = idx >> 6, px = idx & 63;
        float ox = s_om[n * OMS + px];
        float oy = s_om[(9 + n) * OMS + px];
        float mk = s_om[(18 + n) * OMS + px];
        float pxf = ox + (float)(n / 3 - 1) + (float)(h + 1);
        float pyf = oy + (float)(n % 3 - 1) + (float)(w0 + px + 1);
        float fx = floorf(pxf), fy = floorf(pyf);
        int qxlt = (int)fminf(fmaxf(fx, 0.f), 129.f);
        int qylt = (int)fminf(fmaxf(fy, 0.f), 129.f);
        int qxrb = (int)fminf(fmaxf(fx + 1.f, 0.f), 129.f);
        int qyrb = (int)fminf(fmaxf(fy + 1.f, 0.f), 129.f);
        float pxc = fminf(fmaxf(pxf, 0.f), 129.f);
        float pyc = fminf(fmaxf(pyf, 0.f), 129.f);
        float ax = 1.f + (float)qxlt - pxc;
        float bx = 1.f - ((float)qxrb - pxc);
        float ay = 1.f + (float)qylt - pyc;
        float by = 1.f - ((float)qyrb - pyc);
        int* g = &s_geo[idx * 8];
        g[0] = (qxlt * WP + qylt) * 64;
        g[1] = (qxrb * WP + qyrb) * 64;
        g[2] = (qxlt * WP + qyrb) * 64;
        g[3] = (qxrb * WP + qylt) * 64;
        reinterpret_cast<float*>(g)[4] = ax * ay * mk;
        reinterpret_cast<float*>(g)[5] = bx * by * mk;
        reinterpret_cast<float*>(g)[6] = ax * by * mk;
        reinterpret_cast<float*>(g)[7] = bx * ay * mk;
    }
    __syncthreads();

    // ---- phase D: deformable sampling + GEMM, gathers pipelined 1 iter ahead ----
    f32x4 acc[2];
    #pragma unroll
    for (int g = 0; g < 2; ++g) {
        acc[g][0] = 0.f; acc[g][1] = 0.f; acc[g][2] = 0.f; acc[g][3] = 0.f;
    }

    const unsigned short* wbase = wtt + (size_t)(wid & 3) * 9216;   // frag-major, 1KB/wave-instr
    int px_s = t >> 3;          // sampling: 64 px
    int cig_s = t & 7;          // 8-ci-vec chunk
    int coff = cig_s * 8;
    char* xoff_base = reinterpret_cast<char*>(su.d.xoff);
    int ghalf = wid >> 2;       // px-half for MFMA role

    // prologue: issue n=0 gathers
    bf16x8 c0, c1, c2, c3;
    {
        const int* gp = &s_geo[px_s * 8];
        int a0 = gp[0], a1 = gp[1], a2 = gp[2], a3 = gp[3];
        c0 = *reinterpret_cast<const bf16x8*>(xtb + a0 + coff);
        c1 = *reinterpret_cast<const bf16x8*>(xtb + a1 + coff);
        c2 = *reinterpret_cast<const bf16x8*>(xtb + a2 + coff);
        c3 = *reinterpret_cast<const bf16x8*>(xtb + a3 + coff);
    }

    for (int n = 0; n < NPT; ++n) {
        // issue next-iter gathers before consuming current
        bf16x8 d0 = c0, d1 = c1, d2 = c2, d3 = c3;
        if (n < NPT - 1) {
            const int* gpn = &s_geo[((n + 1) * 64 + px_s) * 8];
            int na0 = gpn[0], na1 = gpn[1], na2 = gpn[2], na3 = gpn[3];
            d0 = *reinterpret_cast<const bf16x8*>(xtb + na0 + coff);
            d1 = *reinterpret_cast<const bf16x8*>(xtb + na1 + coff);
            d2 = *reinterpret_cast<const bf16x8*>(xtb + na2 + coff);
            d3 = *reinterpret_cast<const bf16x8*>(xtb + na3 + coff);
        }
        // B fragments for this n (contiguous 1KB per wave)
        bf16x8 bf0 = *reinterpret_cast<const bf16x8*>(wbase + n * 1024 + lhi * 128 + ln15 * 8);
        bf16x8 bf1 = *reinterpret_cast<const bf16x8*>(wbase + n * 1024 + 512 + lhi * 128 + ln15 * 8);

        const float* wp = reinterpret_cast<const float*>(&s_geo[(n * 64 + px_s) * 8]) + 4;
        float glt = wp[0], grb = wp[1], glb = wp[2], grt = wp[3];

        unsigned int pk[4];
        #pragma unroll
        for (int i = 0; i < 4; ++i) {
            float va = glt * bf2f((unsigned short)c0[2*i])   + grb * bf2f((unsigned short)c1[2*i])
                     + glb * bf2f((unsigned short)c2[2*i])   + grt * bf2f((unsigned short)c3[2*i]);
            float vb = glt * bf2f((unsigned short)c0[2*i+1]) + grb * bf2f((unsigned short)c1[2*i+1])
                     + glb * bf2f((unsigned short)c2[2*i+1]) + grt * bf2f((unsigned short)c3[2*i+1]);
            pk[i] = (unsigned int)f2bf(va) | ((unsigned int)f2bf(vb) << 16);
        }
        {
            char* base = xoff_base + px_s * 128;
            int sw = (px_s & 7) << 4;
            *reinterpret_cast<int4*>(base + ((cig_s * 16) ^ sw)) = *reinterpret_cast<int4*>(&pk[0]);
        }
        __syncthreads();

        #pragma unroll
        for (int s2 = 0; s2 < 2; ++s2) {
            bf16x8 bfr = s2 ? bf1 : bf0;
            #pragma unroll
            for (int g = 0; g < 2; ++g) {
                int row = (ghalf * 2 + g) * 16 + ln15;
                int cb2 = (s2 * 32 + lhi * 8) * 2;
                bf16x8 af = *reinterpret_cast<const bf16x8*>(
                    xoff_base + row * 128 + (cb2 ^ ((row & 7) << 4)));
                acc[g] = __builtin_amdgcn_mfma_f32_16x16x32_bf16(af, bfr, acc[g], 0, 0, 0);
            }
        }
        __syncthreads();

        c0 = d0; c1 = d1; c2 = d2; c3 = d3;
    }

    // ---- epilogue ----
    int co = (wid & 3) * 16 + ln15;
    float* orow = out + ((size_t)b * CC + co) * HW + h * WW + w0;
    #pragma unroll
    for (int g = 0; g < 2; ++g) {
        *reinterpret_cast<float4*>(orow + (ghalf * 2 + g) * 16 + lhi * 4) =
            *reinterpret_cast<float4*>(&acc[g]);
    }
}

extern "C" void kernel_launch(void* const* d_in, const int* in_sizes, int n_in,
                              void* d_out, int out_size, void* d_ws, size_t ws_size,
                              hipStream_t stream) {
    const float* x  = (const float*)d_in[0];
    const float* pw = (const float*)d_in[1];
    const float* pb = (const float*)d_in[2];
    const float* mw = (const float*)d_in[3];
    const float* mb = (const float*)d_in[4];
    const float* cw = (const float*)d_in[5];
    float* out = (float*)d_out;

    char* wsc = (char*)d_ws;
    unsigned short* xt  = (unsigned short*)wsc;                         // 4*130*130*64 bf16
    size_t off = ((size_t)BB * HP * WP * 64 * 2 + 255) & ~(size_t)255;
    unsigned short* wtt = (unsigned short*)(wsc + off);                 // 36864 bf16, frag-major
    off += (size_t)64 * 576 * 2;
    unsigned short* wttB = (unsigned short*)(wsc + off);                // 18432 bf16
    off += (size_t)18432 * 2;
    float* b27 = (float*)(wsc + ((off + 255) & ~(size_t)255));          // 32 f32

    int prep_items = 36864 + 18432 + 32 + BB * 4128;
    hipLaunchKernelGGL(k_prep, dim3((prep_items + 255) / 256), dim3(256), 0, stream,
                       cw, pw, pb, mw, mb, wtt, wttB, b27, xt);
    hipLaunchKernelGGL(k_nhwc, dim3(BB * HH), dim3(256), 0, stream, x, xt);
    hipLaunchKernelGGL(k_fused, dim3(BB * HH * 2), dim3(512), 0, stream,
                       xt, wttB, b27, wtt, out);
}

// Round 10
// 40.939 us; speedup vs baseline: 12.5410x; 1.1114x over previous
//
#include <hip/hip_runtime.h>
#include <hip/hip_bf16.h>
#include <math.h>

#define BB 4
#define CC 64
#define HH 128
#define WW 128
#define NPT 9
#define HW (HH*WW)
#define HP 130
#define WP 130

typedef __attribute__((ext_vector_type(8))) short bf16x8;
typedef __attribute__((ext_vector_type(4))) float f32x4;

static __device__ __forceinline__ unsigned short f2bf(float f) {
    __hip_bfloat16 h = __float2bfloat16(f);
    return *reinterpret_cast<unsigned short*>(&h);
}
static __device__ __forceinline__ float bf2f(unsigned short u) {
    return __uint_as_float(((unsigned int)u) << 16);
}

// ---------------- kernel 0: NHWC transpose (blocks 0..511) + all prep (blocks 512+) ------
// prep flat i: [0,36864) wtt frag-major | [36864,55296) wttB | [55296,55328) b27 | pad-zero
__global__ __launch_bounds__(256) void k_pre(
    const float* __restrict__ x, const float* __restrict__ cw,
    const float* __restrict__ pw, const float* __restrict__ pb,
    const float* __restrict__ mw, const float* __restrict__ mb,
    unsigned short* __restrict__ xt, unsigned short* __restrict__ wtt,
    unsigned short* __restrict__ wttB, float* __restrict__ b27)
{
    __shared__ float tile[64][129];
    int bid = blockIdx.x;
    int t = threadIdx.x;
    if (bid < BB * HH) {
        int b = bid >> 7, h = bid & 127;
        const float* xb = x + ((size_t)b * CC) * HW + h * WW;
        #pragma unroll
        for (int i = 0; i < 32; ++i) {
            int idx = i * 256 + t;
            int ci = idx >> 7, w = idx & 127;
            tile[ci][w] = xb[(size_t)ci * HW + w];
        }
        __syncthreads();
        unsigned short* xtb = xt + (((size_t)b * HP + (h + 1)) * WP + 1) * 64;
        #pragma unroll
        for (int i = 0; i < 32; ++i) {
            int idx = i * 256 + t;
            int w = idx >> 6, ci = idx & 63;
            xtb[(size_t)w * 64 + ci] = f2bf(tile[ci][w]);
        }
        return;
    }
    int i = (bid - BB * HH) * 256 + t;
    if (i < 36864) {
        int cot = i / 9216;
        int rem = i - cot * 9216;
        int n   = rem >> 10;
        int s2  = (rem >> 9) & 1;
        int lhi = (rem >> 7) & 3;
        int l15 = (rem >> 3) & 15;
        int j   = i & 7;
        int co = cot * 16 + l15;
        int ci = s2 * 32 + lhi * 8 + j;
        wtt[i] = f2bf(cw[(co * 64 + ci) * 9 + n]);
    } else if (i < 55296) {
        int q = i - 36864;
        int j   = q & 7;
        int co  = (q >> 3) & 31;
        int lhi = (q >> 8) & 3;
        int s2  = (q >> 10) & 1;
        int n   = q >> 11;
        int ci  = s2 * 32 + lhi * 8 + j;
        float v = 0.f;
        if (co < 18) v = pw[(co * 64 + ci) * 9 + n];
        else if (co < 27) v = mw[((co - 18) * 64 + ci) * 9 + n];
        wttB[q] = f2bf(v);
    } else if (i < 55328) {
        int co = i - 55296;
        b27[co] = (co < 18) ? pb[co] : (co < 27 ? mb[co - 18] : 0.f);
    } else if (i < 55328 + BB * 4128) {
        int p = i - 55328;
        int b = p / 4128, r = p - b * 4128;
        size_t base;
        if (r < 2080) {
            int row = r / 1040;
            int rr  = r - row * 1040;
            int wp = rr >> 3, c8 = rr & 7;
            int hp = row ? (HP - 1) : 0;
            base = (((size_t)b * HP + hp) * WP + wp) * 64 + c8 * 8;
        } else {
            int r2 = r - 2080;
            int col = r2 >> 10;
            int rr  = r2 & 1023;
            int hp = (rr >> 3) + 1, c8 = rr & 7;
            int wp = col ? (WP - 1) : 0;
            base = (((size_t)b * HP + hp) * WP + wp) * 64 + c8 * 8;
        }
        *reinterpret_cast<int4*>(xt + base) = make_int4(0, 0, 0, 0);
    }
}

// ---------------- fused kernel ----------------
// block: 64 px (half h-row) x 64 co out, 512 threads (8 waves).
#define OMS 68    // s_om row stride (floats)
#define NCX 198   // 3 rows x 66 cols of A-stage chunks

union SmemU {
    struct { int geo[576 * 8]; unsigned int xoff[2][2048]; } d;  // 34816 B (phases G,D)
    unsigned short astage[NCX * 64];                             // 25344 B (phase A)
};

__global__ __launch_bounds__(512, 4) void k_fused(
    const unsigned short* __restrict__ xt, const unsigned short* __restrict__ wttB,
    const float* __restrict__ b27, const unsigned short* __restrict__ wtt,
    float* __restrict__ out)
{
    __shared__ SmemU su;
    __shared__ float s_om[27 * OMS];

    // XCD-chunked swizzle: 1024 blocks, 8 XCDs
    int blk0 = blockIdx.x;
    int blk = (blk0 & 7) * 128 + (blk0 >> 3);
    int wblk = blk & 1;
    int h = (blk >> 1) & 127;
    int b = blk >> 8;
    int w0 = wblk * 64;
    int t = threadIdx.x;
    int ln = t & 63, wid = t >> 6;          // 8 waves
    int ln15 = ln & 15, lhi = ln >> 4;

    const unsigned short* xtb = xt + (size_t)b * HP * WP * 64;
    char* astage_c = reinterpret_cast<char*>(su.astage);

    // ---- phase S: stage A-tile rows h..h+2, cols w0..w0+65, swizzled ----
    for (int uu = t; uu < NCX * 8; uu += 512) {
        int cx = uu >> 3, o16 = uu & 7;
        int r = cx / 66, c = cx - r * 66;
        const unsigned short* src = xtb + ((size_t)(h + r) * WP + (w0 + c)) * 64 + o16 * 8;
        int4 v = *reinterpret_cast<const int4*>(src);
        *reinterpret_cast<int4*>(astage_c + cx * 128 + ((o16 ^ (cx & 7)) << 4)) = v;
    }
    __syncthreads();

    // ---- phase A: offset/mask conv via MFMA (A from LDS, B pipelined), -> s_om ----
    {
        int pxg = wid >> 1, coh = wid & 1;     // wave quadrant: 16 px x 16 co
        int px = pxg * 16 + ln15;
        f32x4 acc;
        acc[0] = 0.f; acc[1] = 0.f; acc[2] = 0.f; acc[3] = 0.f;
        const unsigned short* wB = wttB + (size_t)(coh * 16 + ln15) * 8 + lhi * 256;
        bf16x8 bfc = *reinterpret_cast<const bf16x8*>(wB);       // ns = 0
        #pragma unroll
        for (int ns = 0; ns < 18; ++ns) {
            bf16x8 bfn = bfc;
            if (ns < 17)
                bfn = *reinterpret_cast<const bf16x8*>(wB + (size_t)(ns + 1) * 1024);
            int n = ns >> 1, s2 = ns & 1;
            int kh = n / 3, kw = n - kh * 3;
            int cx = kh * 66 + px + kw;
            int o16 = s2 * 4 + lhi;
            bf16x8 af = *reinterpret_cast<const bf16x8*>(
                astage_c + cx * 128 + ((o16 ^ (cx & 7)) << 4));
            acc = __builtin_amdgcn_mfma_f32_16x16x32_bf16(af, bfc, acc, 0, 0, 0);
            bfc = bfn;
        }
        int co = coh * 16 + ln15;
        int prow = pxg * 16 + lhi * 4;
        if (co < 27) {
            float bias = b27[co];
            float4 v;
            v.x = acc[0] + bias; v.y = acc[1] + bias;
            v.z = acc[2] + bias; v.w = acc[3] + bias;
            if (co >= 18) {
                v.x = 1.f / (1.f + expf(-v.x));
                v.y = 1.f / (1.f + expf(-v.y));
                v.z = 1.f / (1.f + expf(-v.z));
                v.w = 1.f / (1.f + expf(-v.w));
            }
            *reinterpret_cast<float4*>(&s_om[co * OMS + prow]) = v;
        }
    }
    __syncthreads();

    int* s_geo = su.d.geo;

    // ---- phase G: geometry for 9 n x 64 px (overwrites astage region) ----
    for (int idx = t; idx < NPT * 64; idx += 512) {
        int n = idx >> 6, px = idx & 63;
        float ox = s_om[n * OMS + px];
        float oy = s_om[(9 + n) * OMS + px];
        float mk = s_om[(18 + n) * OMS + px];
        float pxf = ox + (float)(n / 3 - 1) + (float)(h + 1);
        float pyf = oy + (float)(n % 3 - 1) + (float)(w0 + px + 1);
        float fx = floorf(pxf), fy = floorf(pyf);
        int qxlt = (int)fminf(fmaxf(fx, 0.f), 129.f);
        int qylt = (int)fminf(fmaxf(fy, 0.f), 129.f);
        int qxrb = (int)fminf(fmaxf(fx + 1.f, 0.f), 129.f);
        int qyrb = (int)fminf(fmaxf(fy + 1.f, 0.f), 129.f);
        float pxc = fminf(fmaxf(pxf, 0.f), 129.f);
        float pyc = fminf(fmaxf(pyf, 0.f), 129.f);
        float ax = 1.f + (float)qxlt - pxc;
        float bx = 1.f - ((float)qxrb - pxc);
        float ay = 1.f + (float)qylt - pyc;
        float by = 1.f - ((float)qyrb - pyc);
        int* g = &s_geo[idx * 8];
        g[0] = (qxlt * WP + qylt) * 64;
        g[1] = (qxrb * WP + qyrb) * 64;
        g[2] = (qxlt * WP + qyrb) * 64;
        g[3] = (qxrb * WP + qylt) * 64;
        reinterpret_cast<float*>(g)[4] = ax * ay * mk;
        reinterpret_cast<float*>(g)[5] = bx * by * mk;
        reinterpret_cast<float*>(g)[6] = ax * by * mk;
        reinterpret_cast<float*>(g)[7] = bx * ay * mk;
    }
    __syncthreads();

    // ---- phase D: sampling + GEMM; xoff double-buffered, 1 barrier/n, gathers 2-deep ----
    f32x4 acc[2];
    #pragma unroll
    for (int g = 0; g < 2; ++g) {
        acc[g][0] = 0.f; acc[g][1] = 0.f; acc[g][2] = 0.f; acc[g][3] = 0.f;
    }

    const unsigned short* wbase = wtt + (size_t)(wid & 3) * 9216;   // frag-major
    int px_s = t >> 3;          // sampling: 64 px
    int cig_s = t & 7;          // 8-ci-vec chunk
    int coff = cig_s * 8;
    char* xoff_base = reinterpret_cast<char*>(su.d.xoff);
    int ghalf = wid >> 2;       // px-half for MFMA role
    int wsw = (cig_s * 16) ^ ((px_s & 7) << 4);   // swizzled write offset within row

    bf16x8 ga0, ga1, ga2, ga3, gb0, gb1, gb2, gb3;

#define GATHER(S0, S1, S2, S3, NN) do {                                        \
        const int* gp_ = &s_geo[((NN) * 64 + px_s) * 8];                       \
        S0 = *reinterpret_cast<const bf16x8*>(xtb + gp_[0] + coff);            \
        S1 = *reinterpret_cast<const bf16x8*>(xtb + gp_[1] + coff);            \
        S2 = *reinterpret_cast<const bf16x8*>(xtb + gp_[2] + coff);            \
        S3 = *reinterpret_cast<const bf16x8*>(xtb + gp_[3] + coff);            \
    } while (0)

#define PACK(S0, S1, S2, S3, NN) do {                                          \
        const float* wp_ = reinterpret_cast<const float*>(                     \
            &s_geo[((NN) * 64 + px_s) * 8]) + 4;                               \
        float glt_ = wp_[0], grb_ = wp_[1], glb_ = wp_[2], grt_ = wp_[3];      \
        unsigned int pk_[4];                                                   \
        _Pragma("unroll")                                                      \
        for (int i_ = 0; i_ < 4; ++i_) {                                       \
            float va_ = glt_ * bf2f((unsigned short)S0[2*i_])                  \
                      + grb_ * bf2f((unsigned short)S1[2*i_])                  \
                      + glb_ * bf2f((unsigned short)S2[2*i_])                  \
                      + grt_ * bf2f((unsigned short)S3[2*i_]);                 \
            float vb_ = glt_ * bf2f((unsigned short)S0[2*i_+1])                \
                      + grb_ * bf2f((unsigned short)S1[2*i_+1])                \
                      + glb_ * bf2f((unsigned short)S2[2*i_+1])                \
                      + grt_ * bf2f((unsigned short)S3[2*i_+1]);               \
            pk_[i_] = (unsigned int)f2bf(va_) | ((unsigned int)f2bf(vb_) << 16); \
        }                                                                      \
        *reinterpret_cast<int4*>(xoff_base + ((NN) & 1) * 8192 + px_s * 128 + wsw) \
            = *reinterpret_cast<int4*>(&pk_[0]);                               \
    } while (0)

#define MFMA_N(NN) do {                                                        \
        bf16x8 bf0_ = *reinterpret_cast<const bf16x8*>(                        \
            wbase + (NN) * 1024 + lhi * 128 + ln15 * 8);                       \
        bf16x8 bf1_ = *reinterpret_cast<const bf16x8*>(                        \
            wbase + (NN) * 1024 + 512 + lhi * 128 + ln15 * 8);                 \
        char* rbuf_ = xoff_base + ((NN) & 1) * 8192;                           \
        _Pragma("unroll")                                                      \
        for (int s2_ = 0; s2_ < 2; ++s2_) {                                    \
            bf16x8 bfr_ = s2_ ? bf1_ : bf0_;                                   \
            _Pragma("unroll")                                                  \
            for (int g_ = 0; g_ < 2; ++g_) {                                   \
                int row_ = (ghalf * 2 + g_) * 16 + ln15;                       \
                int cb2_ = (s2_ * 32 + lhi * 8) * 2;                           \
                bf16x8 af_ = *reinterpret_cast<const bf16x8*>(                 \
                    rbuf_ + row_ * 128 + (cb2_ ^ ((row_ & 7) << 4)));          \
                acc[g_] = __builtin_amdgcn_mfma_f32_16x16x32_bf16(             \
                    af_, bfr_, acc[g_], 0, 0, 0);                              \
            }                                                                  \
        }                                                                      \
    } while (0)

    // prologue: gathers for n=0,1; pack n=0 -> buf0
    GATHER(ga0, ga1, ga2, ga3, 0);
    GATHER(gb0, gb1, gb2, gb3, 1);
    PACK(ga0, ga1, ga2, ga3, 0);
    __syncthreads();

    // DSTEP(n, SNEW=set[n&1] receives n+2, SPK=set[(n+1)&1] holds n+1)
#define DSTEP(NN, N0, N1, N2, N3, P0, P1, P2, P3) do {                         \
        if ((NN) + 2 < NPT) GATHER(N0, N1, N2, N3, (NN) + 2);                  \
        MFMA_N(NN);                                                            \
        if ((NN) + 1 < NPT) {                                                  \
            PACK(P0, P1, P2, P3, (NN) + 1);                                    \
            __syncthreads();                                                   \
        }                                                                      \
    } while (0)

    DSTEP(0, ga0, ga1, ga2, ga3, gb0, gb1, gb2, gb3);
    DSTEP(1, gb0, gb1, gb2, gb3, ga0, ga1, ga2, ga3);
    DSTEP(2, ga0, ga1, ga2, ga3, gb0, gb1, gb2, gb3);
    DSTEP(3, gb0, gb1, gb2, gb3, ga0, ga1, ga2, ga3);
    DSTEP(4, ga0, ga1, ga2, ga3, gb0, gb1, gb2, gb3);
    DSTEP(5, gb0, gb1, gb2, gb3, ga0, ga1, ga2, ga3);
    DSTEP(6, ga0, ga1, ga2, ga3, gb0, gb1, gb2, gb3);
    DSTEP(7, gb0, gb1, gb2, gb3, ga0, ga1, ga2, ga3);
    DSTEP(8, ga0, ga1, ga2, ga3, gb0, gb1, gb2, gb3);

    // ---- epilogue ----
    int co = (wid & 3) * 16 + ln15;
    float* orow = out + ((size_t)b * CC + co) * HW + h * WW + w0;
    #pragma unroll
    for (int g = 0; g < 2; ++g) {
        *reinterpret_cast<float4*>(orow + (ghalf * 2 + g) * 16 + lhi * 4) =
            *reinterpret_cast<float4*>(&acc[g]);
    }
}

extern "C" void kernel_launch(void* const* d_in, const int* in_sizes, int n_in,
                              void* d_out, int out_size, void* d_ws, size_t ws_size,
                              hipStream_t stream) {
    const float* x  = (const float*)d_in[0];
    const float* pw = (const float*)d_in[1];
    const float* pb = (const float*)d_in[2];
    const float* mw = (const float*)d_in[3];
    const float* mb = (const float*)d_in[4];
    const float* cw = (const float*)d_in[5];
    float* out = (float*)d_out;

    char* wsc = (char*)d_ws;
    unsigned short* xt  = (unsigned short*)wsc;                         // 4*130*130*64 bf16
    size_t off = ((size_t)BB * HP * WP * 64 * 2 + 255) & ~(size_t)255;
    unsigned short* wtt = (unsigned short*)(wsc + off);                 // 36864 bf16, frag-major
    off += (size_t)64 * 576 * 2;
    unsigned short* wttB = (unsigned short*)(wsc + off);                // 18432 bf16
    off += (size_t)18432 * 2;
    float* b27 = (float*)(wsc + ((off + 255) & ~(size_t)255));          // 32 f32

    int prep_items = 36864 + 18432 + 32 + BB * 4128;
    int prep_blocks = (prep_items + 255) / 256;
    hipLaunchKernelGGL(k_pre, dim3(BB * HH + prep_blocks), dim3(256), 0, stream,
                       x, cw, pw, pb, mw, mb, xt, wtt, wttB, b27);
    hipLaunchKernelGGL(k_fused, dim3(BB * HH * 2), dim3(512), 0, stream,
                       xt, wttB, b27, wtt, out);
}

// Round 11
// 40.363 us; speedup vs baseline: 12.7198x; 1.0143x over previous
//
#include <hip/hip_runtime.h>
#include <hip/hip_bf16.h>
#include <math.h>

#define BB 4
#define CC 64
#define HH 128
#define WW 128
#define NPT 9
#define HW (HH*WW)
#define HP 130
#define WP 130

typedef __attribute__((ext_vector_type(8))) short bf16x8;
typedef __attribute__((ext_vector_type(4))) float f32x4;

static __device__ __forceinline__ unsigned short f2bf(float f) {
    __hip_bfloat16 h = __float2bfloat16(f);
    return *reinterpret_cast<unsigned short*>(&h);
}
static __device__ __forceinline__ float bf2f(unsigned short u) {
    return __uint_as_float(((unsigned int)u) << 16);
}

// ---------------- kernel 0: NHWC transpose (blocks 0..511) + all prep (blocks 512+) ------
// prep flat i: [0,36864) wtt frag-major | [36864,55296) wttB | [55296,55328) b27 | pad-zero
__global__ __launch_bounds__(256) void k_pre(
    const float* __restrict__ x, const float* __restrict__ cw,
    const float* __restrict__ pw, const float* __restrict__ pb,
    const float* __restrict__ mw, const float* __restrict__ mb,
    unsigned short* __restrict__ xt, unsigned short* __restrict__ wtt,
    unsigned short* __restrict__ wttB, float* __restrict__ b27)
{
    __shared__ float tile[64][132];        // stride 132: 16B-aligned rows for b128 LDS ops
    int bid = blockIdx.x;
    int t = threadIdx.x;
    if (bid < BB * HH) {
        int b = bid >> 7, h = bid & 127;
        const float* xb = x + ((size_t)b * CC) * HW + h * WW;
        #pragma unroll
        for (int i = 0; i < 8; ++i) {
            int idx = i * 256 + t;             // 2048 float4 over 64ci x 32 w4
            int ci = idx >> 5, w4 = idx & 31;
            float4 v = *reinterpret_cast<const float4*>(xb + (size_t)ci * HW + w4 * 4);
            *reinterpret_cast<float4*>(&tile[ci][w4 * 4]) = v;
        }
        __syncthreads();
        unsigned short* xtb = xt + (((size_t)b * HP + (h + 1)) * WP + 1) * 64;
        #pragma unroll
        for (int i = 0; i < 4; ++i) {
            int idx = i * 256 + t;             // 1024 items: w(128) x cig(8)
            int w = idx >> 3, cig = idx & 7;
            unsigned int pk[4];
            #pragma unroll
            for (int k = 0; k < 4; ++k) {
                unsigned int u0 = f2bf(tile[cig * 8 + 2 * k][w]);
                unsigned int u1 = f2bf(tile[cig * 8 + 2 * k + 1][w]);
                pk[k] = u0 | (u1 << 16);
            }
            *reinterpret_cast<int4*>(xtb + (size_t)w * 64 + cig * 8) =
                *reinterpret_cast<int4*>(&pk[0]);
        }
        return;
    }
    int i = (bid - BB * HH) * 256 + t;
    if (i < 36864) {
        int cot = i / 9216;
        int rem = i - cot * 9216;
        int n   = rem >> 10;
        int s2  = (rem >> 9) & 1;
        int lhi = (rem >> 7) & 3;
        int l15 = (rem >> 3) & 15;
        int j   = i & 7;
        int co = cot * 16 + l15;
        int ci = s2 * 32 + lhi * 8 + j;
        wtt[i] = f2bf(cw[(co * 64 + ci) * 9 + n]);
    } else if (i < 55296) {
        int q = i - 36864;
        int j   = q & 7;
        int co  = (q >> 3) & 31;
        int lhi = (q >> 8) & 3;
        int s2  = (q >> 10) & 1;
        int n   = q >> 11;
        int ci  = s2 * 32 + lhi * 8 + j;
        float v = 0.f;
        if (co < 18) v = pw[(co * 64 + ci) * 9 + n];
        else if (co < 27) v = mw[((co - 18) * 64 + ci) * 9 + n];
        wttB[q] = f2bf(v);
    } else if (i < 55328) {
        int co = i - 55296;
        b27[co] = (co < 18) ? pb[co] : (co < 27 ? mb[co - 18] : 0.f);
    } else if (i < 55328 + BB * 4128) {
        int p = i - 55328;
        int b = p / 4128, r = p - b * 4128;
        size_t base;
        if (r < 2080) {
            int row = r / 1040;
            int rr  = r - row * 1040;
            int wp = rr >> 3, c8 = rr & 7;
            int hp = row ? (HP - 1) : 0;
            base = (((size_t)b * HP + hp) * WP + wp) * 64 + c8 * 8;
        } else {
            int r2 = r - 2080;
            int col = r2 >> 10;
            int rr  = r2 & 1023;
            int hp = (rr >> 3) + 1, c8 = rr & 7;
            int wp = col ? (WP - 1) : 0;
            base = (((size_t)b * HP + hp) * WP + wp) * 64 + c8 * 8;
        }
        *reinterpret_cast<int4*>(xt + base) = make_int4(0, 0, 0, 0);
    }
}

// ---------------- fused kernel ----------------
// block: 64 px (half h-row) x 64 co out, 512 threads (8 waves).
#define OMS 68    // s_om row stride (floats)
#define NCX 198   // 3 rows x 66 cols of A-stage chunks

union SmemU {
    struct { int geo[576 * 8]; unsigned int xoff[2][2048]; } d;  // 34816 B (phases G,D)
    unsigned short astage[NCX * 64];                             // 25344 B (phase A)
};

__global__ __launch_bounds__(512, 4) void k_fused(
    const unsigned short* __restrict__ xt, const unsigned short* __restrict__ wttB,
    const float* __restrict__ b27, const unsigned short* __restrict__ wtt,
    float* __restrict__ out)
{
    __shared__ SmemU su;
    __shared__ float s_om[27 * OMS];

    // XCD-chunked swizzle: 1024 blocks, 8 XCDs
    int blk0 = blockIdx.x;
    int blk = (blk0 & 7) * 128 + (blk0 >> 3);
    int wblk = blk & 1;
    int h = (blk >> 1) & 127;
    int b = blk >> 8;
    int w0 = wblk * 64;
    int t = threadIdx.x;
    int ln = t & 63, wid = t >> 6;          // 8 waves
    int ln15 = ln & 15, lhi = ln >> 4;

    const unsigned short* xtb = xt + (size_t)b * HP * WP * 64;
    char* astage_c = reinterpret_cast<char*>(su.astage);

    // ---- phase S: stage A-tile rows h..h+2, cols w0..w0+65, swizzled ----
    for (int uu = t; uu < NCX * 8; uu += 512) {
        int cx = uu >> 3, o16 = uu & 7;
        int r = cx / 66, c = cx - r * 66;
        const unsigned short* src = xtb + ((size_t)(h + r) * WP + (w0 + c)) * 64 + o16 * 8;
        int4 v = *reinterpret_cast<const int4*>(src);
        *reinterpret_cast<int4*>(astage_c + cx * 128 + ((o16 ^ (cx & 7)) << 4)) = v;
    }
    __syncthreads();

    // ---- phase A: offset/mask conv via MFMA (A from LDS, B pipelined), -> s_om ----
    {
        int pxg = wid >> 1, coh = wid & 1;     // wave quadrant: 16 px x 16 co
        int px = pxg * 16 + ln15;
        f32x4 acc;
        acc[0] = 0.f; acc[1] = 0.f; acc[2] = 0.f; acc[3] = 0.f;
        const unsigned short* wB = wttB + (size_t)(coh * 16 + ln15) * 8 + lhi * 256;
        bf16x8 bfc = *reinterpret_cast<const bf16x8*>(wB);       // ns = 0
        #pragma unroll
        for (int ns = 0; ns < 18; ++ns) {
            bf16x8 bfn = bfc;
            if (ns < 17)
                bfn = *reinterpret_cast<const bf16x8*>(wB + (size_t)(ns + 1) * 1024);
            int n = ns >> 1, s2 = ns & 1;
            int kh = n / 3, kw = n - kh * 3;
            int cx = kh * 66 + px + kw;
            int o16 = s2 * 4 + lhi;
            bf16x8 af = *reinterpret_cast<const bf16x8*>(
                astage_c + cx * 128 + ((o16 ^ (cx & 7)) << 4));
            acc = __builtin_amdgcn_mfma_f32_16x16x32_bf16(af, bfc, acc, 0, 0, 0);
            bfc = bfn;
        }
        int co = coh * 16 + ln15;
        int prow = pxg * 16 + lhi * 4;
        if (co < 27) {
            float bias = b27[co];
            float4 v;
            v.x = acc[0] + bias; v.y = acc[1] + bias;
            v.z = acc[2] + bias; v.w = acc[3] + bias;
            if (co >= 18) {
                v.x = 1.f / (1.f + expf(-v.x));
                v.y = 1.f / (1.f + expf(-v.y));
                v.z = 1.f / (1.f + expf(-v.z));
                v.w = 1.f / (1.f + expf(-v.w));
            }
            *reinterpret_cast<float4*>(&s_om[co * OMS + prow]) = v;
        }
    }
    __syncthreads();

    int* s_geo = su.d.geo;

    // ---- phase G: geometry for 9 n x 64 px; layout [float4 w][int4 addr] ----
    for (int idx = t; idx < NPT * 64; idx += 512) {
        int n = idx >> 6, px = idx & 63;
        float ox = s_om[n * OMS + px];
        float oy = s_om[(9 + n) * OMS + px];
        float mk = s_om[(18 + n) * OMS + px];
        float pxf = ox + (float)(n / 3 - 1) + (float)(h + 1);
        float pyf = oy + (float)(n % 3 - 1) + (float)(w0 + px + 1);
        float fx = floorf(pxf), fy = floorf(pyf);
        int qxlt = (int)fminf(fmaxf(fx, 0.f), 129.f);
        int qylt = (int)fminf(fmaxf(fy, 0.f), 129.f);
        int qxrb = (int)fminf(fmaxf(fx + 1.f, 0.f), 129.f);
        int qyrb = (int)fminf(fmaxf(fy + 1.f, 0.f), 129.f);
        float pxc = fminf(fmaxf(pxf, 0.f), 129.f);
        float pyc = fminf(fmaxf(pyf, 0.f), 129.f);
        float ax = 1.f + (float)qxlt - pxc;
        float bx = 1.f - ((float)qxrb - pxc);
        float ay = 1.f + (float)qylt - pyc;
        float by = 1.f - ((float)qyrb - pyc);
        int* g = &s_geo[idx * 8];
        float4 wv;
        wv.x = ax * ay * mk;   // lt
        wv.y = bx * by * mk;   // rb
        wv.z = ax * by * mk;   // lb
        wv.w = bx * ay * mk;   // rt
        int4 av;
        av.x = (qxlt * WP + qylt) * 64;
        av.y = (qxrb * WP + qyrb) * 64;
        av.z = (qxlt * WP + qyrb) * 64;
        av.w = (qxrb * WP + qylt) * 64;
        *reinterpret_cast<float4*>(g) = wv;
        *reinterpret_cast<int4*>(g + 4) = av;
    }
    __syncthreads();

    // ---- phase D: sampling + GEMM; xoff double-buffered, 1 barrier/n, gathers 2-deep ----
    f32x4 acc[2];
    #pragma unroll
    for (int g = 0; g < 2; ++g) {
        acc[g][0] = 0.f; acc[g][1] = 0.f; acc[g][2] = 0.f; acc[g][3] = 0.f;
    }

    const unsigned short* wbase = wtt + (size_t)(wid & 3) * 9216;   // frag-major
    int px_s = t >> 3;          // sampling: 64 px
    int cig_s = t & 7;          // 8-ci-vec chunk
    int coff = cig_s * 8;
    char* xoff_base = reinterpret_cast<char*>(su.d.xoff);
    int ghalf = wid >> 2;       // px-half for MFMA role
    int wsw = (cig_s * 16) ^ ((px_s & 7) << 4);   // swizzled write offset within row

    bf16x8 ga0, ga1, ga2, ga3, gb0, gb1, gb2, gb3;

#define GATHER(S0, S1, S2, S3, NN) do {                                        \
        const int4 av_ = *reinterpret_cast<const int4*>(                       \
            &s_geo[((NN) * 64 + px_s) * 8] + 4);                               \
        S0 = *reinterpret_cast<const bf16x8*>(xtb + av_.x + coff);             \
        S1 = *reinterpret_cast<const bf16x8*>(xtb + av_.y + coff);             \
        S2 = *reinterpret_cast<const bf16x8*>(xtb + av_.z + coff);             \
        S3 = *reinterpret_cast<const bf16x8*>(xtb + av_.w + coff);             \
    } while (0)

#define PACK(S0, S1, S2, S3, NN) do {                                          \
        const float4 wv_ = *reinterpret_cast<const float4*>(                   \
            &s_geo[((NN) * 64 + px_s) * 8]);                                   \
        unsigned int pk_[4];                                                   \
        _Pragma("unroll")                                                      \
        for (int i_ = 0; i_ < 4; ++i_) {                                       \
            float va_ = wv_.x * bf2f((unsigned short)S0[2*i_])                 \
                      + wv_.y * bf2f((unsigned short)S1[2*i_])                 \
                      + wv_.z * bf2f((unsigned short)S2[2*i_])                 \
                      + wv_.w * bf2f((unsigned short)S3[2*i_]);                \
            float vb_ = wv_.x * bf2f((unsigned short)S0[2*i_+1])               \
                      + wv_.y * bf2f((unsigned short)S1[2*i_+1])               \
                      + wv_.z * bf2f((unsigned short)S2[2*i_+1])               \
                      + wv_.w * bf2f((unsigned short)S3[2*i_+1]);              \
            pk_[i_] = __builtin_amdgcn_perm(__float_as_uint(vb_),              \
                                            __float_as_uint(va_), 0x07060302u); \
        }                                                                      \
        *reinterpret_cast<int4*>(xoff_base + ((NN) & 1) * 8192 + px_s * 128 + wsw) \
            = *reinterpret_cast<int4*>(&pk_[0]);                               \
    } while (0)

#define MFMA_N(NN) do {                                                        \
        bf16x8 bf0_ = *reinterpret_cast<const bf16x8*>(                        \
            wbase + (NN) * 1024 + lhi * 128 + ln15 * 8);                       \
        bf16x8 bf1_ = *reinterpret_cast<const bf16x8*>(                        \
            wbase + (NN) * 1024 + 512 + lhi * 128 + ln15 * 8);                 \
        char* rbuf_ = xoff_base + ((NN) & 1) * 8192;                           \
        _Pragma("unroll")                                                      \
        for (int s2_ = 0; s2_ < 2; ++s2_) {                                    \
            bf16x8 bfr_ = s2_ ? bf1_ : bf0_;                                   \
            _Pragma("unroll")                                                  \
            for (int g_ = 0; g_ < 2; ++g_) {                                   \
                int row_ = (ghalf * 2 + g_) * 16 + ln15;                       \
                int cb2_ = (s2_ * 32 + lhi * 8) * 2;                           \
                bf16x8 af_ = *reinterpret_cast<const bf16x8*>(                 \
                    rbuf_ + row_ * 128 + (cb2_ ^ ((row_ & 7) << 4)));          \
                acc[g_] = __builtin_amdgcn_mfma_f32_16x16x32_bf16(             \
                    af_, bfr_, acc[g_], 0, 0, 0);                              \
            }                                                                  \
        }                                                                      \
    } while (0)

    // prologue: gathers for n=0,1; pack n=0 -> buf0
    GATHER(ga0, ga1, ga2, ga3, 0);
    GATHER(gb0, gb1, gb2, gb3, 1);
    PACK(ga0, ga1, ga2, ga3, 0);
    __syncthreads();

#define DSTEP(NN, N0, N1, N2, N3, P0, P1, P2, P3) do {                         \
        if ((NN) + 2 < NPT) GATHER(N0, N1, N2, N3, (NN) + 2);                  \
        MFMA_N(NN);                                                            \
        if ((NN) + 1 < NPT) {                                                  \
            PACK(P0, P1, P2, P3, (NN) + 1);                                    \
            __syncthreads();                                                   \
        }                                                                      \
    } while (0)

    DSTEP(0, ga0, ga1, ga2, ga3, gb0, gb1, gb2, gb3);
    DSTEP(1, gb0, gb1, gb2, gb3, ga0, ga1, ga2, ga3);
    DSTEP(2, ga0, ga1, ga2, ga3, gb0, gb1, gb2, gb3);
    DSTEP(3, gb0, gb1, gb2, gb3, ga0, ga1, ga2, ga3);
    DSTEP(4, ga0, ga1, ga2, ga3, gb0, gb1, gb2, gb3);
    DSTEP(5, gb0, gb1, gb2, gb3, ga0, ga1, ga2, ga3);
    DSTEP(6, ga0, ga1, ga2, ga3, gb0, gb1, gb2, gb3);
    DSTEP(7, gb0, gb1, gb2, gb3, ga0, ga1, ga2, ga3);
    DSTEP(8, ga0, ga1, ga2, ga3, gb0, gb1, gb2, gb3);

    // ---- epilogue ----
    int co = (wid & 3) * 16 + ln15;
    float* orow = out + ((size_t)b * CC + co) * HW + h * WW + w0;
    #pragma unroll
    for (int g = 0; g < 2; ++g) {
        *reinterpret_cast<float4*>(orow + (ghalf * 2 + g) * 16 + lhi * 4) =
            *reinterpret_cast<float4*>(&acc[g]);
    }
}

extern "C" void kernel_launch(void* const* d_in, const int* in_sizes, int n_in,
                              void* d_out, int out_size, void* d_ws, size_t ws_size,
                              hipStream_t stream) {
    const float* x  = (const float*)d_in[0];
    const float* pw = (const float*)d_in[1];
    const float* pb = (const float*)d_in[2];
    const float* mw = (const float*)d_in[3];
    const float* mb = (const float*)d_in[4];
    const float* cw = (const float*)d_in[5];
    float* out = (float*)d_out;

    char* wsc = (char*)d_ws;
    unsigned short* xt  = (unsigned short*)wsc;                         // 4*130*130*64 bf16
    size_t off = ((size_t)BB * HP * WP * 64 * 2 + 255) & ~(size_t)255;
    unsigned short* wtt = (unsigned short*)(wsc + off);                 // 36864 bf16, frag-major
    off += (size_t)64 * 576 * 2;
    unsigned short* wttB = (unsigned short*)(wsc + off);                // 18432 bf16
    off += (size_t)18432 * 2;
    float* b27 = (float*)(wsc + ((off + 255) & ~(size_t)255));          // 32 f32

    int prep_items = 36864 + 18432 + 32 + BB * 4128;
    int prep_blocks = (prep_items + 255) / 256;
    hipLaunchKernelGGL(k_pre, dim3(BB * HH + prep_blocks), dim3(256), 0, stream,
                       x, cw, pw, pb, mw, mb, xt, wtt, wttB, b27);
    hipLaunchKernelGGL(k_fused, dim3(BB * HH * 2), dim3(512), 0, stream,
                       xt, wttB, b27, wtt, out);
}

// Round 12
// 40.308 us; speedup vs baseline: 12.7372x; 1.0014x over previous
//
#include <hip/hip_runtime.h>
#include <hip/hip_bf16.h>
#include <math.h>

#define BB 4
#define CC 64
#define HH 128
#define WW 128
#define NPT 9
#define HW (HH*WW)
#define HP 130
#define WP 130

typedef __attribute__((ext_vector_type(8))) short bf16x8;
typedef __attribute__((ext_vector_type(4))) float f32x4;

static __device__ __forceinline__ unsigned short f2bf(float f) {
    __hip_bfloat16 h = __float2bfloat16(f);
    return *reinterpret_cast<unsigned short*>(&h);
}
static __device__ __forceinline__ float bf2f(unsigned short u) {
    return __uint_as_float(((unsigned int)u) << 16);
}

// ---------------- kernel 0: NHWC transpose (blocks 0..511) + all prep (blocks 512+) ------
// prep flat i: [0,36864) wtt frag-major | [36864,55296) wttB | [55296,55328) b27 | pad-zero
__global__ __launch_bounds__(256) void k_pre(
    const float* __restrict__ x, const float* __restrict__ cw,
    const float* __restrict__ pw, const float* __restrict__ pb,
    const float* __restrict__ mw, const float* __restrict__ mb,
    unsigned short* __restrict__ xt, unsigned short* __restrict__ wtt,
    unsigned short* __restrict__ wttB, float* __restrict__ b27)
{
    __shared__ float tile[64][132];        // stride 132: 16B-aligned rows for b128 LDS ops
    int bid = blockIdx.x;
    int t = threadIdx.x;
    if (bid < BB * HH) {
        int b = bid >> 7, h = bid & 127;
        const float* xb = x + ((size_t)b * CC) * HW + h * WW;
        #pragma unroll
        for (int i = 0; i < 8; ++i) {
            int idx = i * 256 + t;             // 2048 float4 over 64ci x 32 w4
            int ci = idx >> 5, w4 = idx & 31;
            float4 v = *reinterpret_cast<const float4*>(xb + (size_t)ci * HW + w4 * 4);
            *reinterpret_cast<float4*>(&tile[ci][w4 * 4]) = v;
        }
        __syncthreads();
        unsigned short* xtb = xt + (((size_t)b * HP + (h + 1)) * WP + 1) * 64;
        #pragma unroll
        for (int i = 0; i < 4; ++i) {
            int idx = i * 256 + t;             // 1024 items: w(128) x cig(8)
            int w = idx >> 3, cig = idx & 7;
            unsigned int pk[4];
            #pragma unroll
            for (int k = 0; k < 4; ++k) {
                unsigned int u0 = f2bf(tile[cig * 8 + 2 * k][w]);
                unsigned int u1 = f2bf(tile[cig * 8 + 2 * k + 1][w]);
                pk[k] = u0 | (u1 << 16);
            }
            *reinterpret_cast<int4*>(xtb + (size_t)w * 64 + cig * 8) =
                *reinterpret_cast<int4*>(&pk[0]);
        }
        return;
    }
    int i = (bid - BB * HH) * 256 + t;
    if (i < 36864) {
        int cot = i / 9216;
        int rem = i - cot * 9216;
        int n   = rem >> 10;
        int s2  = (rem >> 9) & 1;
        int lhi = (rem >> 7) & 3;
        int l15 = (rem >> 3) & 15;
        int j   = i & 7;
        int co = cot * 16 + l15;
        int ci = s2 * 32 + lhi * 8 + j;
        wtt[i] = f2bf(cw[(co * 64 + ci) * 9 + n]);
    } else if (i < 55296) {
        int q = i - 36864;
        int j   = q & 7;
        int co  = (q >> 3) & 31;
        int lhi = (q >> 8) & 3;
        int s2  = (q >> 10) & 1;
        int n   = q >> 11;
        int ci  = s2 * 32 + lhi * 8 + j;
        float v = 0.f;
        if (co < 18) v = pw[(co * 64 + ci) * 9 + n];
        else if (co < 27) v = mw[((co - 18) * 64 + ci) * 9 + n];
        wttB[q] = f2bf(v);
    } else if (i < 55328) {
        int co = i - 55296;
        b27[co] = (co < 18) ? pb[co] : (co < 27 ? mb[co - 18] : 0.f);
    } else if (i < 55328 + BB * 4128) {
        int p = i - 55328;
        int b = p / 4128, r = p - b * 4128;
        size_t base;
        if (r < 2080) {
            int row = r / 1040;
            int rr  = r - row * 1040;
            int wp = rr >> 3, c8 = rr & 7;
            int hp = row ? (HP - 1) : 0;
            base = (((size_t)b * HP + hp) * WP + wp) * 64 + c8 * 8;
        } else {
            int r2 = r - 2080;
            int col = r2 >> 10;
            int rr  = r2 & 1023;
            int hp = (rr >> 3) + 1, c8 = rr & 7;
            int wp = col ? (WP - 1) : 0;
            base = (((size_t)b * HP + hp) * WP + wp) * 64 + c8 * 8;
        }
        *reinterpret_cast<int4*>(xt + base) = make_int4(0, 0, 0, 0);
    }
}

// ---------------- fused kernel ----------------
// block: 64 px (half h-row) x 64 co out, 512 threads (8 waves).
#define OMS 68    // s_om row stride (floats)
#define NCX 198   // 3 rows x 66 cols of A-stage chunks

// LDS overlay (34816 B total -> 4 blocks/CU, single residency round for 1024 blocks):
//   phase S/A : astage (25344)            [s_om write happens AFTER a barrier ending astage reads]
//   phase A->G: s_om (7344, aliases bytes 18432..25776)
//   phase G->D: geo (18432, bytes 0..18432)
//   phase D   : xoff[2] (16384, aliases s_om region; first write after G's barrier)
union SmemU {
    unsigned short astage[NCX * 64];                 // 25344 B
    struct {
        int geo[576 * 8];                            // 18432 B
        union {
            float om[27 * OMS];                      // 7344 B
            unsigned int xoff[2][2048];              // 16384 B
        } u2;
    } d;                                             // 34816 B
};

__global__ __launch_bounds__(512, 4) void k_fused(
    const unsigned short* __restrict__ xt, const unsigned short* __restrict__ wttB,
    const float* __restrict__ b27, const unsigned short* __restrict__ wtt,
    float* __restrict__ out)
{
    __shared__ SmemU su;

    // XCD-chunked swizzle: 1024 blocks, 8 XCDs
    int blk0 = blockIdx.x;
    int blk = (blk0 & 7) * 128 + (blk0 >> 3);
    int wblk = blk & 1;
    int h = (blk >> 1) & 127;
    int b = blk >> 8;
    int w0 = wblk * 64;
    int t = threadIdx.x;
    int ln = t & 63, wid = t >> 6;          // 8 waves
    int ln15 = ln & 15, lhi = ln >> 4;

    const unsigned short* xtb = xt + (size_t)b * HP * WP * 64;
    char* astage_c = reinterpret_cast<char*>(su.astage);
    float* s_om = su.d.u2.om;

    // ---- phase S: stage A-tile rows h..h+2, cols w0..w0+65, swizzled ----
    for (int uu = t; uu < NCX * 8; uu += 512) {
        int cx = uu >> 3, o16 = uu & 7;
        int r = cx / 66, c = cx - r * 66;
        const unsigned short* src = xtb + ((size_t)(h + r) * WP + (w0 + c)) * 64 + o16 * 8;
        int4 v = *reinterpret_cast<const int4*>(src);
        *reinterpret_cast<int4*>(astage_c + cx * 128 + ((o16 ^ (cx & 7)) << 4)) = v;
    }
    __syncthreads();

    // ---- phase A: offset/mask conv via MFMA (A from LDS, B pipelined), -> s_om ----
    {
        int pxg = wid >> 1, coh = wid & 1;     // wave quadrant: 16 px x 16 co
        int px = pxg * 16 + ln15;
        f32x4 acc;
        acc[0] = 0.f; acc[1] = 0.f; acc[2] = 0.f; acc[3] = 0.f;
        const unsigned short* wB = wttB + (size_t)(coh * 16 + ln15) * 8 + lhi * 256;
        bf16x8 bfc = *reinterpret_cast<const bf16x8*>(wB);       // ns = 0
        #pragma unroll
        for (int ns = 0; ns < 18; ++ns) {
            bf16x8 bfn = bfc;
            if (ns < 17)
                bfn = *reinterpret_cast<const bf16x8*>(wB + (size_t)(ns + 1) * 1024);
            int n = ns >> 1, s2 = ns & 1;
            int kh = n / 3, kw = n - kh * 3;
            int cx = kh * 66 + px + kw;
            int o16 = s2 * 4 + lhi;
            bf16x8 af = *reinterpret_cast<const bf16x8*>(
                astage_c + cx * 128 + ((o16 ^ (cx & 7)) << 4));
            acc = __builtin_amdgcn_mfma_f32_16x16x32_bf16(af, bfc, acc, 0, 0, 0);
            bfc = bfn;
        }
        // barrier: all astage reads complete before s_om (aliasing) writes
        __syncthreads();
        int co = coh * 16 + ln15;
        int prow = pxg * 16 + lhi * 4;
        if (co < 27) {
            float bias = b27[co];
            float4 v;
            v.x = acc[0] + bias; v.y = acc[1] + bias;
            v.z = acc[2] + bias; v.w = acc[3] + bias;
            if (co >= 18) {
                v.x = 1.f / (1.f + expf(-v.x));
                v.y = 1.f / (1.f + expf(-v.y));
                v.z = 1.f / (1.f + expf(-v.z));
                v.w = 1.f / (1.f + expf(-v.w));
            }
            *reinterpret_cast<float4*>(&s_om[co * OMS + prow]) = v;
        }
    }
    __syncthreads();

    int* s_geo = su.d.geo;

    // ---- phase G: geometry for 9 n x 64 px; layout [float4 w][int4 addr] ----
    for (int idx = t; idx < NPT * 64; idx += 512) {
        int n = idx >> 6, px = idx & 63;
        float ox = s_om[n * OMS + px];
        float oy = s_om[(9 + n) * OMS + px];
        float mk = s_om[(18 + n) * OMS + px];
        float pxf = ox + (float)(n / 3 - 1) + (float)(h + 1);
        float pyf = oy + (float)(n % 3 - 1) + (float)(w0 + px + 1);
        float fx = floorf(pxf), fy = floorf(pyf);
        int qxlt = (int)fminf(fmaxf(fx, 0.f), 129.f);
        int qylt = (int)fminf(fmaxf(fy, 0.f), 129.f);
        int qxrb = (int)fminf(fmaxf(fx + 1.f, 0.f), 129.f);
        int qyrb = (int)fminf(fmaxf(fy + 1.f, 0.f), 129.f);
        float pxc = fminf(fmaxf(pxf, 0.f), 129.f);
        float pyc = fminf(fmaxf(pyf, 0.f), 129.f);
        float ax = 1.f + (float)qxlt - pxc;
        float bx = 1.f - ((float)qxrb - pxc);
        float ay = 1.f + (float)qylt - pyc;
        float by = 1.f - ((float)qyrb - pyc);
        int* g = &s_geo[idx * 8];
        float4 wv;
        wv.x = ax * ay * mk;   // lt
        wv.y = bx * by * mk;   // rb
        wv.z = ax * by * mk;   // lb
        wv.w = bx * ay * mk;   // rt
        int4 av;
        av.x = (qxlt * WP + qylt) * 64;
        av.y = (qxrb * WP + qyrb) * 64;
        av.z = (qxlt * WP + qyrb) * 64;
        av.w = (qxrb * WP + qylt) * 64;
        *reinterpret_cast<float4*>(g) = wv;
        *reinterpret_cast<int4*>(g + 4) = av;
    }
    __syncthreads();

    // ---- phase D: sampling + GEMM; xoff double-buffered, 1 barrier/n, gathers 2-deep ----
    f32x4 acc[2];
    #pragma unroll
    for (int g = 0; g < 2; ++g) {
        acc[g][0] = 0.f; acc[g][1] = 0.f; acc[g][2] = 0.f; acc[g][3] = 0.f;
    }

    const unsigned short* wbase = wtt + (size_t)(wid & 3) * 9216;   // frag-major
    int px_s = t >> 3;          // sampling: 64 px
    int cig_s = t & 7;          // 8-ci-vec chunk
    int coff = cig_s * 8;
    char* xoff_base = reinterpret_cast<char*>(su.d.u2.xoff);
    int ghalf = wid >> 2;       // px-half for MFMA role
    int wsw = (cig_s * 16) ^ ((px_s & 7) << 4);   // swizzled write offset within row

    bf16x8 ga0, ga1, ga2, ga3, gb0, gb1, gb2, gb3;

#define GATHER(S0, S1, S2, S3, NN) do {                                        \
        const int4 av_ = *reinterpret_cast<const int4*>(                       \
            &s_geo[((NN) * 64 + px_s) * 8] + 4);                               \
        S0 = *reinterpret_cast<const bf16x8*>(xtb + av_.x + coff);             \
        S1 = *reinterpret_cast<const bf16x8*>(xtb + av_.y + coff);             \
        S2 = *reinterpret_cast<const bf16x8*>(xtb + av_.z + coff);             \
        S3 = *reinterpret_cast<const bf16x8*>(xtb + av_.w + coff);             \
    } while (0)

#define PACK(S0, S1, S2, S3, NN) do {                                          \
        const float4 wv_ = *reinterpret_cast<const float4*>(                   \
            &s_geo[((NN) * 64 + px_s) * 8]);                                   \
        unsigned int pk_[4];                                                   \
        _Pragma("unroll")                                                      \
        for (int i_ = 0; i_ < 4; ++i_) {                                       \
            float va_ = wv_.x * bf2f((unsigned short)S0[2*i_])                 \
                      + wv_.y * bf2f((unsigned short)S1[2*i_])                 \
                      + wv_.z * bf2f((unsigned short)S2[2*i_])                 \
                      + wv_.w * bf2f((unsigned short)S3[2*i_]);                \
            float vb_ = wv_.x * bf2f((unsigned short)S0[2*i_+1])               \
                      + wv_.y * bf2f((unsigned short)S1[2*i_+1])               \
                      + wv_.z * bf2f((unsigned short)S2[2*i_+1])               \
                      + wv_.w * bf2f((unsigned short)S3[2*i_+1]);              \
            pk_[i_] = __builtin_amdgcn_perm(__float_as_uint(vb_),              \
                                            __float_as_uint(va_), 0x07060302u); \
        }                                                                      \
        *reinterpret_cast<int4*>(xoff_base + ((NN) & 1) * 8192 + px_s * 128 + wsw) \
            = *reinterpret_cast<int4*>(&pk_[0]);                               \
    } while (0)

#define MFMA_N(NN) do {                                                        \
        bf16x8 bf0_ = *reinterpret_cast<const bf16x8*>(                        \
            wbase + (NN) * 1024 + lhi * 128 + ln15 * 8);                       \
        bf16x8 bf1_ = *reinterpret_cast<const bf16x8*>(                        \
            wbase + (NN) * 1024 + 512 + lhi * 128 + ln15 * 8);                 \
        char* rbuf_ = xoff_base + ((NN) & 1) * 8192;                           \
        _Pragma("unroll")                                                      \
        for (int s2_ = 0; s2_ < 2; ++s2_) {                                    \
            bf16x8 bfr_ = s2_ ? bf1_ : bf0_;                                   \
            _Pragma("unroll")                                                  \
            for (int g_ = 0; g_ < 2; ++g_) {                                   \
                int row_ = (ghalf * 2 + g_) * 16 + ln15;                       \
                int cb2_ = (s2_ * 32 + lhi * 8) * 2;                           \
                bf16x8 af_ = *reinterpret_cast<const bf16x8*>(                 \
                    rbuf_ + row_ * 128 + (cb2_ ^ ((row_ & 7) << 4)));          \
                acc[g_] = __builtin_amdgcn_mfma_f32_16x16x32_bf16(             \
                    af_, bfr_, acc[g_], 0, 0, 0);                              \
            }                                                                  \
        }                                                                      \
    } while (0)

    // prologue: gathers for n=0,1; pack n=0 -> buf0
    GATHER(ga0, ga1, ga2, ga3, 0);
    GATHER(gb0, gb1, gb2, gb3, 1);
    PACK(ga0, ga1, ga2, ga3, 0);
    __syncthreads();

#define DSTEP(NN, N0, N1, N2, N3, P0, P1, P2, P3) do {                         \
        if ((NN) + 2 < NPT) GATHER(N0, N1, N2, N3, (NN) + 2);                  \
        MFMA_N(NN);                                                            \
        if ((NN) + 1 < NPT) {                                                  \
            PACK(P0, P1, P2, P3, (NN) + 1);                                    \
            __syncthreads();                                                   \
        }                                                                      \
    } while (0)

    DSTEP(0, ga0, ga1, ga2, ga3, gb0, gb1, gb2, gb3);
    DSTEP(1, gb0, gb1, gb2, gb3, ga0, ga1, ga2, ga3);
    DSTEP(2, ga0, ga1, ga2, ga3, gb0, gb1, gb2, gb3);
    DSTEP(3, gb0, gb1, gb2, gb3, ga0, ga1, ga2, ga3);
    DSTEP(4, ga0, ga1, ga2, ga3, gb0, gb1, gb2, gb3);
    DSTEP(5, gb0, gb1, gb2, gb3, ga0, ga1, ga2, ga3);
    DSTEP(6, ga0, ga1, ga2, ga3, gb0, gb1, gb2, gb3);
    DSTEP(7, gb0, gb1, gb2, gb3, ga0, ga1, ga2, ga3);
    DSTEP(8, ga0, ga1, ga2, ga3, gb0, gb1, gb2, gb3);

    // ---- epilogue ----
    int co = (wid & 3) * 16 + ln15;
    float* orow = out + ((size_t)b * CC + co) * HW + h * WW + w0;
    #pragma unroll
    for (int g = 0; g < 2; ++g) {
        *reinterpret_cast<float4*>(orow + (ghalf * 2 + g) * 16 + lhi * 4) =
            *reinterpret_cast<float4*>(&acc[g]);
    }
}

extern "C" void kernel_launch(void* const* d_in, const int* in_sizes, int n_in,
                              void* d_out, int out_size, void* d_ws, size_t ws_size,
                              hipStream_t stream) {
    const float* x  = (const float*)d_in[0];
    const float* pw = (const float*)d_in[1];
    const float* pb = (const float*)d_in[2];
    const float* mw = (const float*)d_in[3];
    const float* mb = (const float*)d_in[4];
    const float* cw = (const float*)d_in[5];
    float* out = (float*)d_out;

    char* wsc = (char*)d_ws;
    unsigned short* xt  = (unsigned short*)wsc;                         // 4*130*130*64 bf16
    size_t off = ((size_t)BB * HP * WP * 64 * 2 + 255) & ~(size_t)255;
    unsigned short* wtt = (unsigned short*)(wsc + off);                 // 36864 bf16, frag-major
    off += (size_t)64 * 576 * 2;
    unsigned short* wttB = (unsigned short*)(wsc + off);                // 18432 bf16
    off += (size_t)18432 * 2;
    float* b27 = (float*)(wsc + ((off + 255) & ~(size_t)255));          // 32 f32

    int prep_items = 36864 + 18432 + 32 + BB * 4128;
    int prep_blocks = (prep_items + 255) / 256;
    hipLaunchKernelGGL(k_pre, dim3(BB * HH + prep_blocks), dim3(256), 0, stream,
                       x, cw, pw, pb, mw, mb, xt, wtt, wttB, b27);
    hipLaunchKernelGGL(k_fused, dim3(BB * HH * 2), dim3(512), 0, stream,
                       xt, wttB, b27, wtt, out);
}